// Round 8
// baseline (769.302 us; speedup 1.0000x reference)
//
#include <hip/hip_runtime.h>
#include <hip/hip_bf16.h>
#include <math.h>

// Problem constants
constexpr int Bc = 4;
constexpr int Sc = 2048;
constexpr int Dc = 512;
constexpr int Hc = 8;
constexpr int DHc = 64;
constexpr int Lc = 4;
constexpr int DFFc = 2048;
constexpr int Tc = Bc * Sc;   // 8192 tokens
constexpr int QKVW = 3 * Dc;  // 1536

typedef __attribute__((ext_vector_type(8))) short short8;
typedef __attribute__((ext_vector_type(4))) float f32x4;

static __device__ __forceinline__ float u16tof(unsigned int u) {
  return __uint_as_float(u << 16);
}
static __device__ __forceinline__ unsigned short ftobf(float f) {
  __hip_bfloat16 h = __float2bfloat16(f);
  return *reinterpret_cast<unsigned short*>(&h);
}
static __device__ __forceinline__ void gload_lds16(const void* g, void* l) {
  __builtin_amdgcn_global_load_lds(
      (const __attribute__((address_space(1))) void*)g,
      (__attribute__((address_space(3))) void*)l, 16, 0, 0);
}

// LDS chunk-swizzle helpers for attention (16B-chunk XOR, conflict-free b128)
static __device__ __forceinline__ int swzK(int row, int col) {  // width 64
  return row * 64 + ((((col >> 3) ^ (row & 7)) << 3) | (col & 7));
}
static __device__ __forceinline__ int swzW(int row, int col) {  // width 192
  return row * 192 + ((((col >> 3) ^ (row & 7)) << 3) | (col & 7));
}

// ---------------------------------------------------------------------------
// fp32 -> bf16 conversion (weights, once per launch)
// ---------------------------------------------------------------------------
__global__ __launch_bounds__(256) void k_f2bf(const float* __restrict__ in,
                                              unsigned short* __restrict__ out,
                                              int n) {
  int i = blockIdx.x * 256 + threadIdx.x;
  if (i < n) out[i] = ftobf(in[i]);
}

// ---------------------------------------------------------------------------
// Embed: h = x @ W_in^T + b_in + pos ; also bf16 copy
// ---------------------------------------------------------------------------
__global__ __launch_bounds__(256) void k_embed(const float* __restrict__ x,
                                               const float* __restrict__ W_in,
                                               const float* __restrict__ b_in,
                                               const float* __restrict__ pos,
                                               float* __restrict__ h,
                                               unsigned short* __restrict__ hb) {
  int idx = blockIdx.x * 256 + threadIdx.x;
  int t = idx >> 9;
  int d = idx & 511;
  int s = t & (Sc - 1);
  float v = x[t * 2 + 0] * W_in[d * 2 + 0] + x[t * 2 + 1] * W_in[d * 2 + 1] +
            b_in[d] + pos[(size_t)s * Dc + d];
  h[idx] = v;
  hb[idx] = ftobf(v);
}

// ---------------------------------------------------------------------------
// k_m256: 256x256 tile, 8 waves (2M x 4N), BK=32, FOUR LDS buffers, counted
// vmcnt that NEVER drains in steady state (tile j+3 staged during tile j;
// top-of-tile-j wait = vmcnt(8): tiles j+1, j+2 remain in flight).
// One barrier + one vmcnt per 32-MFMA K-tile. Prefetch lead = 3 K-tiles
// (~6 phases) > HBM latency.
// LDS per buffer: A,B each 256x32 bf16 (16 KB); granule swizzle
// g_slot = g ^ ((row>>1)&3) -> 16-lane frag b128 reads hit 8 bank-quads
// (2-way, free). Staging: inverse-permuted global src, linear LDS dest.
//   MODE 0: +bias ; MODE 2: +bias, exact GELU.  OUTBF 1: bf16 out.
// ---------------------------------------------------------------------------
template <int MODE, int OUTBF, int KK>
__global__ __launch_bounds__(512, 2) void k_m256(const unsigned short* __restrict__ A,
                                                 const unsigned short* __restrict__ W,
                                                 const float* __restrict__ bias,
                                                 void* __restrict__ Cout,
                                                 int M, int N) {
  constexpr int NT = KK / 32;  // K-tiles
  __shared__ unsigned short Asb[4][256 * 32];
  __shared__ unsigned short Bsb[4][256 * 32];
  const int tid = threadIdx.x;
  const int lane = tid & 63;
  const int wid = tid >> 6;
  const int wm = wid >> 2;  // 0..1 (M half)
  const int wn = wid & 3;   // 0..3 (N quarter)

  // XCD-aware block swizzle (grids here: 256 / 192 blocks, %8==0)
  const int nwg = gridDim.x * gridDim.y;
  const int bid = blockIdx.y * gridDim.x + blockIdx.x;
  const int sbid = (bid & 7) * (nwg >> 3) + (bid >> 3);
  const int m0 = (sbid / gridDim.x) * 256;
  const int n0 = (sbid % gridDim.x) * 256;

  // Staging geometry: tile = 256 rows x 4 granules(16B) = 1024 granules;
  // 2 instrs x 512 threads. Instr i, thread t covers LDS granule p=i*512+t
  // (linear dest). Source: row = p>>2, slot g = p&3, src granule
  // gs = g ^ ((row>>1)&3).
  int rowS[2], gsS[2];
#pragma unroll
  for (int i = 0; i < 2; ++i) {
    int p = i * 512 + tid;
    rowS[i] = p >> 2;
    gsS[i] = (p & 3) ^ ((rowS[i] >> 1) & 3);
  }
  const unsigned short* ApS[2];
  const unsigned short* WpS[2];
#pragma unroll
  for (int i = 0; i < 2; ++i) {
    ApS[i] = A + (size_t)(m0 + rowS[i]) * KK + gsS[i] * 8;
    WpS[i] = W + (size_t)(n0 + rowS[i]) * KK + gsS[i] * 8;
  }
  // LDS dest byte offsets (wave-uniform base + lane*16 is the HW pattern)
  const int dst0 = (tid & ~63) * 16;
  const int dst1 = 8192 + dst0;

  f32x4 acc[8][4] = {};
  const int lr = lane & 15;
  const int lg = lane >> 4;  // K-granule of the fragment

  // prologue: stage tiles 0,1,2 (per tile: A x2, B x2 -- order matters for vmcnt)
#pragma unroll
  for (int t = 0; t < 3; ++t) {
    const int ko = t * 32;
    gload_lds16(ApS[0] + ko, (char*)&Asb[t][0] + dst0);
    gload_lds16(ApS[1] + ko, (char*)&Asb[t][0] + dst1);
    gload_lds16(WpS[0] + ko, (char*)&Bsb[t][0] + dst0);
    gload_lds16(WpS[1] + ko, (char*)&Bsb[t][0] + dst1);
  }

  for (int j = 0; j < NT; ++j) {
    // wait for tile j only; keep tiles j+1, j+2 in flight
    if (j <= NT - 3) {
      asm volatile("s_waitcnt vmcnt(8)" ::: "memory");
    } else if (j == NT - 2) {
      asm volatile("s_waitcnt vmcnt(4)" ::: "memory");
    } else {
      asm volatile("s_waitcnt vmcnt(0)" ::: "memory");
    }
    __builtin_amdgcn_s_barrier();
    __builtin_amdgcn_sched_barrier(0);

    const int b = j & 3;
    const bool st = (j + 3 < NT);
    const int ko = (j + 3) * 32;
    const int nb = (j + 3) & 3;

    // ---------- phase 0: mi 0..3 x ni 0..3 ----------
    if (st) {  // stage A of tile j+3
      gload_lds16(ApS[0] + ko, (char*)&Asb[nb][0] + dst0);
      gload_lds16(ApS[1] + ko, (char*)&Asb[nb][0] + dst1);
    }
    short8 af[4], bf[4];
#pragma unroll
    for (int mi = 0; mi < 4; ++mi) {
      int r = wm * 128 + mi * 16 + lr;
      af[mi] = *(const short8*)&Asb[b][r * 32 + ((lg ^ ((r >> 1) & 3)) << 3)];
    }
#pragma unroll
    for (int ni = 0; ni < 4; ++ni) {
      int r = wn * 64 + ni * 16 + lr;
      bf[ni] = *(const short8*)&Bsb[b][r * 32 + ((lg ^ ((r >> 1) & 3)) << 3)];
    }
    asm volatile("s_waitcnt lgkmcnt(0)" ::: "memory");
    __builtin_amdgcn_sched_barrier(0);
    __builtin_amdgcn_s_setprio(1);
#pragma unroll
    for (int mi = 0; mi < 4; ++mi)
#pragma unroll
      for (int ni = 0; ni < 4; ++ni)
        acc[mi][ni] = __builtin_amdgcn_mfma_f32_16x16x32_bf16(
            af[mi], bf[ni], acc[mi][ni], 0, 0, 0);
    __builtin_amdgcn_s_setprio(0);

    // ---------- phase 1: mi 4..7 x ni 0..3 (B reused in regs) ----------
    if (st) {  // stage B of tile j+3
      gload_lds16(WpS[0] + ko, (char*)&Bsb[nb][0] + dst0);
      gload_lds16(WpS[1] + ko, (char*)&Bsb[nb][0] + dst1);
    }
    short8 af2[4];
#pragma unroll
    for (int mi = 0; mi < 4; ++mi) {
      int r = wm * 128 + (mi + 4) * 16 + lr;
      af2[mi] = *(const short8*)&Asb[b][r * 32 + ((lg ^ ((r >> 1) & 3)) << 3)];
    }
    asm volatile("s_waitcnt lgkmcnt(0)" ::: "memory");
    __builtin_amdgcn_sched_barrier(0);
    __builtin_amdgcn_s_setprio(1);
#pragma unroll
    for (int mi = 0; mi < 4; ++mi)
#pragma unroll
      for (int ni = 0; ni < 4; ++ni)
        acc[mi + 4][ni] = __builtin_amdgcn_mfma_f32_16x16x32_bf16(
            af2[mi], bf[ni], acc[mi + 4][ni], 0, 0, 0);
    __builtin_amdgcn_s_setprio(0);
  }

  // epilogue: C/D layout col = lane&15 -> n, row = (lane>>4)*4 + jj -> m
  const int cj = lane & 15;
  const int rj = (lane >> 4) * 4;
#pragma unroll
  for (int mi = 0; mi < 8; ++mi) {
#pragma unroll
    for (int ni = 0; ni < 4; ++ni) {
      int n = n0 + wn * 64 + ni * 16 + cj;
      float bn = bias[n];
#pragma unroll
      for (int jj = 0; jj < 4; ++jj) {
        int m = m0 + wm * 128 + mi * 16 + rj + jj;
        float v = acc[mi][ni][jj] + bn;
        if (MODE == 2) v = 0.5f * v * (1.0f + erff(v * 0.70710678118654752f));
        if (OUTBF)
          ((unsigned short*)Cout)[(size_t)m * N + n] = ftobf(v);
        else
          ((float*)Cout)[(size_t)m * N + n] = v;
      }
    }
  }
}

// ---------------------------------------------------------------------------
// k_wgemm: 64x64 tile, one wave per block, no barriers (Wo / W2 shapes).
// Depth-2 ping-pong, counted vmcnt. unroll 1 caps code size (K=2048: 64 steps).
// ---------------------------------------------------------------------------
template <int MODE, int OUTBF, int KK>
__global__ __launch_bounds__(64) void k_wgemm(const unsigned short* __restrict__ A,
                                              const unsigned short* __restrict__ W,
                                              const float* __restrict__ bias,
                                              const float* __restrict__ res,
                                              void* __restrict__ Cout,
                                              int M, int N) {
  constexpr int NSTEP = KK / 32;
  __shared__ unsigned short As[2][64 * 32];
  __shared__ unsigned short Bs[2][64 * 32];
  const int lane = threadIdx.x;

  const int nwg = gridDim.x * gridDim.y;
  const int bid = blockIdx.y * gridDim.x + blockIdx.x;
  const int swz = (bid & 7) * (nwg >> 3) + (bid >> 3);
  const int m0 = (swz / gridDim.x) * 64;
  const int n0 = (swz % gridDim.x) * 64;

  const unsigned short* Ap[4];
  const unsigned short* Wp[4];
#pragma unroll
  for (int i = 0; i < 4; ++i) {
    int p = i * 64 + lane;
    int rp = p >> 3, q = (p & 7) ^ (rp & 7);
    int row = (rp << 1) | (q >> 2);
    int ch = q & 3;
    Ap[i] = A + (size_t)(m0 + row) * KK + ch * 8;
    Wp[i] = W + (size_t)(n0 + row) * KK + ch * 8;
  }

  f32x4 acc[4][4] = {};
  const int lr = lane & 15;
  const int chr = lane >> 4;

#pragma unroll
  for (int i = 0; i < 4; ++i) {
    gload_lds16(Ap[i], &As[0][i * 512]);
    gload_lds16(Wp[i], &Bs[0][i * 512]);
  }

#pragma unroll 1
  for (int s = 0; s < NSTEP; ++s) {
    const int buf = s & 1;
    if (s + 1 < NSTEP) {
      const int ko = (s + 1) * 32;
      const int nb = buf ^ 1;
#pragma unroll
      for (int i = 0; i < 4; ++i) {
        gload_lds16(Ap[i] + ko, &As[nb][i * 512]);
        gload_lds16(Wp[i] + ko, &Bs[nb][i * 512]);
      }
      __builtin_amdgcn_sched_barrier(0);
      asm volatile("s_waitcnt vmcnt(8)" ::: "memory");
    } else {
      __builtin_amdgcn_sched_barrier(0);
      asm volatile("s_waitcnt vmcnt(0)" ::: "memory");
    }
    __builtin_amdgcn_sched_barrier(0);

    short8 af[4], bfr[4];
#pragma unroll
    for (int mi = 0; mi < 4; ++mi) {
      int row = mi * 16 + lr;
      int rp = row >> 1;
      int p = rp * 8 + (((((row & 1) << 2) | chr)) ^ (rp & 7));
      af[mi] = *(const short8*)&As[buf][p * 8];
    }
#pragma unroll
    for (int ni = 0; ni < 4; ++ni) {
      int row = ni * 16 + lr;
      int rp = row >> 1;
      int p = rp * 8 + (((((row & 1) << 2) | chr)) ^ (rp & 7));
      bfr[ni] = *(const short8*)&Bs[buf][p * 8];
    }
    asm volatile("s_waitcnt lgkmcnt(0)" ::: "memory");
    __builtin_amdgcn_sched_barrier(0);
#pragma unroll
    for (int mi = 0; mi < 4; ++mi)
#pragma unroll
      for (int ni = 0; ni < 4; ++ni)
        acc[mi][ni] = __builtin_amdgcn_mfma_f32_16x16x32_bf16(
            af[mi], bfr[ni], acc[mi][ni], 0, 0, 0);
  }

  const int cj = lane & 15;
  const int rj = (lane >> 4) * 4;
#pragma unroll
  for (int mi = 0; mi < 4; ++mi) {
#pragma unroll
    for (int ni = 0; ni < 4; ++ni) {
      int n = n0 + ni * 16 + cj;
      float bn = bias[n];
#pragma unroll
      for (int j = 0; j < 4; ++j) {
        int m = m0 + mi * 16 + rj + j;
        float v = acc[mi][ni][j] + bn;
        if (MODE == 1) v += res[(size_t)m * N + n];
        if (MODE == 2) v = 0.5f * v * (1.0f + erff(v * 0.70710678118654752f));
        if (OUTBF)
          ((unsigned short*)Cout)[(size_t)m * N + n] = ftobf(v);
        else
          ((float*)Cout)[(size_t)m * N + n] = v;
      }
    }
  }
}

// ---------------------------------------------------------------------------
// Windowed causal attention, MFMA. qkv bf16 [T][1536].
// ---------------------------------------------------------------------------
__global__ __launch_bounds__(256) void k_attn(const unsigned short* __restrict__ qkv,
                                              unsigned short* __restrict__ o) {
  __shared__ unsigned short Ks[192 * 64];
  __shared__ unsigned short Vt[64 * 192];
  __shared__ unsigned short Ps[64 * 192];

  const int tid = threadIdx.x;
  const int lane = tid & 63;
  const int w = tid >> 6;
  const int idx = blockIdx.x;
  const int qb = idx & 31;
  const int hh = (idx >> 5) & 7;
  const int b = idx >> 8;
  const int q0 = qb * 64;
  const int kstart = max(0, q0 - 128);
  const int nk = q0 + 64 - kstart;  // 64 (qb==0) or 192

  for (int c = tid; c < nk * 8; c += 256) {
    int j = c >> 3, ch = c & 7;
    short8 kv = *(const short8*)&qkv[(size_t)(b * Sc + kstart + j) * QKVW + Dc + hh * DHc + ch * 8];
    *(short8*)&Ks[swzK(j, ch * 8)] = kv;
  }
  for (int c = tid; c < (nk >> 1) * 8; c += 256) {
    int jp = c >> 3, ch = c & 7;
    int j = jp * 2;
    const unsigned short* base =
        &qkv[(size_t)(b * Sc + kstart + j) * QKVW + 2 * Dc + hh * DHc + ch * 8];
    short8 v0 = *(const short8*)base;
    short8 v1 = *(const short8*)(base + QKVW);
#pragma unroll
    for (int i = 0; i < 8; ++i) {
      unsigned int pk = (unsigned short)v0[i] | ((unsigned int)(unsigned short)v1[i] << 16);
      *(unsigned int*)&Vt[swzW(ch * 8 + i, j)] = pk;
    }
  }
  if (nk < 192) {
    for (int c = tid; c < 64 * 64; c += 256) {
      int d = c >> 6, jo = c & 63;
      *(unsigned int*)&Vt[swzW(d, 64 + jo * 2)] = 0;
    }
  }

  const int qg = q0 + w * 16 + (lane & 15);
  const int kg8 = (lane >> 4) * 8;
  const unsigned short* qp = &qkv[(size_t)(b * Sc + qg) * QKVW + hh * DHc + kg8];
  short8 bq0 = *(const short8*)qp;
  short8 bq1 = *(const short8*)(qp + 32);
  __syncthreads();

  const int jb = max(0, q0 + w * 16 - 128) - kstart;

  f32x4 sacc[9];
#pragma unroll
  for (int t = 0; t < 9; ++t) {
    int key = jb + t * 16 + (lane & 15);
    short8 a0 = *(const short8*)&Ks[swzK(key, kg8)];
    short8 a1 = *(const short8*)&Ks[swzK(key, 32 + kg8)];
    f32x4 z = {0.f, 0.f, 0.f, 0.f};
    z = __builtin_amdgcn_mfma_f32_16x16x32_bf16(a0, bq0, z, 0, 0, 0);
    sacc[t] = __builtin_amdgcn_mfma_f32_16x16x32_bf16(a1, bq1, z, 0, 0, 0);
  }

  const int rj = (lane >> 4) * 4;
  float mx = -1e30f;
#pragma unroll
  for (int t = 0; t < 9; ++t) {
#pragma unroll
    for (int j = 0; j < 4; ++j) {
      int kglob = kstart + jb + t * 16 + rj + j;
      bool valid = (kglob <= qg) && (kglob + 128 >= qg);
      float s = valid ? sacc[t][j] * 0.125f : -1e30f;
      sacc[t][j] = s;
      mx = fmaxf(mx, s);
    }
  }
  mx = fmaxf(mx, __shfl_xor(mx, 16));
  mx = fmaxf(mx, __shfl_xor(mx, 32));
  float sum = 0.f;
#pragma unroll
  for (int t = 0; t < 9; ++t)
#pragma unroll
    for (int j = 0; j < 4; ++j) {
      float e = __expf(sacc[t][j] - mx);
      sacc[t][j] = e;
      sum += e;
    }
  sum += __shfl_xor(sum, 16);
  sum += __shfl_xor(sum, 32);
  const float inv = 1.0f / sum;

  const int prow = w * 16 + (lane & 15);
#pragma unroll
  for (int t = 0; t < 9; ++t) {
    int c0 = jb + t * 16 + rj;
    unsigned int p0 = ftobf(sacc[t][0] * inv) |
                      ((unsigned int)ftobf(sacc[t][1] * inv) << 16);
    unsigned int p1 = ftobf(sacc[t][2] * inv) |
                      ((unsigned int)ftobf(sacc[t][3] * inv) << 16);
    *(unsigned int*)&Ps[swzW(prow, c0)] = p0;
    *(unsigned int*)&Ps[swzW(prow, c0 + 2)] = p1;
  }
  {
    int g2 = (lane >> 4) * 2;
    for (int col = g2; col < jb; col += 8)
      *(unsigned int*)&Ps[swzW(prow, col)] = 0;
    for (int col = jb + 144 + g2; col < 192; col += 8)
      *(unsigned int*)&Ps[swzW(prow, col)] = 0;
  }
  f32x4 oacc[4] = {};
#pragma unroll
  for (int kb = 0; kb < 6; ++kb) {
    short8 pa = *(const short8*)&Ps[swzW(prow, kb * 32 + kg8)];
#pragma unroll
    for (int dt = 0; dt < 4; ++dt) {
      short8 vb = *(const short8*)&Vt[swzW(dt * 16 + (lane & 15), kb * 32 + kg8)];
      oacc[dt] = __builtin_amdgcn_mfma_f32_16x16x32_bf16(pa, vb, oacc[dt], 0, 0, 0);
    }
  }
  const int cj = lane & 15;
#pragma unroll
  for (int j = 0; j < 4; ++j)
#pragma unroll
    for (int dt = 0; dt < 4; ++dt)
      o[(size_t)(b * Sc + q0 + w * 16 + rj + j) * Dc + hh * DHc + dt * 16 + cj] =
          ftobf(oacc[dt][j]);
}

// ---------------------------------------------------------------------------
// LayerNorm over D=512, one wave per token; fp32 + bf16 outputs.
// ---------------------------------------------------------------------------
__global__ __launch_bounds__(256) void k_ln(const float* __restrict__ in,
                                            const float* __restrict__ g,
                                            const float* __restrict__ bta,
                                            float* __restrict__ out,
                                            unsigned short* __restrict__ outb) {
  const int wid = threadIdx.x >> 6;
  const int lane = threadIdx.x & 63;
  const int t = blockIdx.x * 4 + wid;
  const float* row = in + (size_t)t * Dc;
  float v[8];
  float sum = 0.0f, sq = 0.0f;
#pragma unroll
  for (int i = 0; i < 8; ++i) {
    float xv = row[lane + i * 64];
    v[i] = xv;
    sum += xv;
    sq += xv * xv;
  }
#pragma unroll
  for (int off = 32; off; off >>= 1) {
    sum += __shfl_xor(sum, off);
    sq += __shfl_xor(sq, off);
  }
  float m = sum * (1.0f / 512.0f);
  float var = sq * (1.0f / 512.0f) - m * m;
  float rstd = rsqrtf(var + 1e-5f);
#pragma unroll
  for (int i = 0; i < 8; ++i) {
    int d = lane + i * 64;
    float ov = (v[i] - m) * rstd * g[d] + bta[d];
    out[(size_t)t * Dc + d] = ov;
    outb[(size_t)t * Dc + d] = ftobf(ov);
  }
}

// ---------------------------------------------------------------------------
// Head (fp32): mu | clipped log_sigma
// ---------------------------------------------------------------------------
__global__ __launch_bounds__(256) void k_head(const float* __restrict__ h,
                                              const float* __restrict__ Wh,
                                              const float* __restrict__ bh,
                                              float* __restrict__ outp) {
  const int wid = threadIdx.x >> 6;
  const int lane = threadIdx.x & 63;
  const int t = blockIdx.x * 4 + wid;
  const float* row = h + (size_t)t * Dc;
  float a0 = 0, a1 = 0, a2 = 0, a3 = 0;
#pragma unroll
  for (int i = 0; i < 8; ++i) {
    int d = lane + i * 64;
    float xv = row[d];
    a0 += xv * Wh[0 * Dc + d];
    a1 += xv * Wh[1 * Dc + d];
    a2 += xv * Wh[2 * Dc + d];
    a3 += xv * Wh[3 * Dc + d];
  }
#pragma unroll
  for (int off = 32; off; off >>= 1) {
    a0 += __shfl_xor(a0, off);
    a1 += __shfl_xor(a1, off);
    a2 += __shfl_xor(a2, off);
    a3 += __shfl_xor(a3, off);
  }
  if (lane == 0) {
    outp[(size_t)t * 2 + 0] = a0 + bh[0];
    outp[(size_t)t * 2 + 1] = a1 + bh[1];
    outp[(size_t)Tc * 2 + (size_t)t * 2 + 0] = fminf(fmaxf(a2 + bh[2], -6.0f), 1.5f);
    outp[(size_t)Tc * 2 + (size_t)t * 2 + 1] = fminf(fmaxf(a3 + bh[3], -6.0f), 1.5f);
  }
}

// ---------------------------------------------------------------------------
extern "C" void kernel_launch(void* const* d_in, const int* in_sizes, int n_in,
                              void* d_out, int out_size, void* d_ws, size_t ws_size,
                              hipStream_t stream) {
  const float* x    = (const float*)d_in[0];
  const float* W_in = (const float*)d_in[1];
  const float* b_in = (const float*)d_in[2];
  const float* pos  = (const float*)d_in[3];
  const float* Wqkv = (const float*)d_in[4];
  const float* bqkv = (const float*)d_in[5];
  const float* Wo   = (const float*)d_in[6];
  const float* bo   = (const float*)d_in[7];
  const float* W1   = (const float*)d_in[8];
  const float* b1   = (const float*)d_in[9];
  const float* W2   = (const float*)d_in[10];
  const float* b2   = (const float*)d_in[11];
  const float* ln1g = (const float*)d_in[12];
  const float* ln1b = (const float*)d_in[13];
  const float* ln2g = (const float*)d_in[14];
  const float* ln2b = (const float*)d_in[15];
  const float* Wh   = (const float*)d_in[16];
  const float* bh   = (const float*)d_in[17];
  float* out = (float*)d_out;

  char* p = (char*)d_ws;
  float* h  = (float*)p;           p += (size_t)Tc * Dc * 4;
  float* t2 = (float*)p;           p += (size_t)Tc * Dc * 4;
  unsigned short* hb  = (unsigned short*)p; p += (size_t)Tc * Dc * 2;
  unsigned short* ob  = (unsigned short*)p; p += (size_t)Tc * Dc * 2;
  unsigned short* big = (unsigned short*)p; p += (size_t)Tc * DFFc * 2;
  unsigned short* wqb = (unsigned short*)p; p += (size_t)Lc * QKVW * Dc * 2;
  unsigned short* wob = (unsigned short*)p; p += (size_t)Lc * Dc * Dc * 2;
  unsigned short* w1b = (unsigned short*)p; p += (size_t)Lc * DFFc * Dc * 2;
  unsigned short* w2b = (unsigned short*)p; p += (size_t)Lc * Dc * DFFc * 2;

  k_f2bf<<<Lc * QKVW * Dc / 256, 256, 0, stream>>>(Wqkv, wqb, Lc * QKVW * Dc);
  k_f2bf<<<Lc * Dc * Dc / 256, 256, 0, stream>>>(Wo, wob, Lc * Dc * Dc);
  k_f2bf<<<Lc * DFFc * Dc / 256, 256, 0, stream>>>(W1, w1b, Lc * DFFc * Dc);
  k_f2bf<<<Lc * Dc * DFFc / 256, 256, 0, stream>>>(W2, w2b, Lc * Dc * DFFc);

  k_embed<<<(Tc * Dc) / 256, 256, 0, stream>>>(x, W_in, b_in, pos, h, hb);

  for (int l = 0; l < Lc; ++l) {
    const unsigned short* wq_l = wqb + (size_t)l * QKVW * Dc;
    const unsigned short* wo_l = wob + (size_t)l * Dc * Dc;
    const unsigned short* w1_l = w1b + (size_t)l * DFFc * Dc;
    const unsigned short* w2_l = w2b + (size_t)l * Dc * DFFc;

    // qkv = hb @ Wqkv^T + bqkv  (bf16 out) -- 256x256 counted-vmcnt kernel
    k_m256<0, 1, Dc><<<dim3(QKVW / 256, Tc / 256), 512, 0, stream>>>(
        hb, wq_l, bqkv + (size_t)l * QKVW, big, Tc, QKVW);

    k_attn<<<Bc * Hc * (Sc / 64), 256, 0, stream>>>(big, ob);

    // t2 = ob @ Wo^T + bo + h  (fp32 out)
    k_wgemm<1, 0, Dc><<<dim3(Dc / 64, Tc / 64), 64, 0, stream>>>(
        ob, wo_l, bo + (size_t)l * Dc, h, t2, Tc, Dc);

    k_ln<<<Tc / 4, 256, 0, stream>>>(t2, ln1g + (size_t)l * Dc, ln1b + (size_t)l * Dc, h, hb);

    // big = gelu(hb @ W1^T + b1)  (bf16 out) -- 256x256 counted-vmcnt kernel
    k_m256<2, 1, Dc><<<dim3(DFFc / 256, Tc / 256), 512, 0, stream>>>(
        hb, w1_l, b1 + (size_t)l * DFFc, big, Tc, DFFc);

    // t2 = big @ W2^T + b2 + h  (fp32 out)
    k_wgemm<1, 0, DFFc><<<dim3(Dc / 64, Tc / 64), 64, 0, stream>>>(
        big, w2_l, b2 + (size_t)l * Dc, h, t2, Tc, Dc);

    k_ln<<<Tc / 4, 256, 0, stream>>>(t2, ln2g + (size_t)l * Dc, ln2b + (size_t)l * Dc, h, hb);
  }

  k_head<<<Tc / 4, 256, 0, stream>>>(h, Wh, bh, out);
}

// Round 9
// 625.922 us; speedup vs baseline: 1.2291x; 1.2291x over previous
//
#include <hip/hip_runtime.h>
#include <hip/hip_bf16.h>
#include <math.h>

// Problem constants
constexpr int Bc = 4;
constexpr int Sc = 2048;
constexpr int Dc = 512;
constexpr int Hc = 8;
constexpr int DHc = 64;
constexpr int Lc = 4;
constexpr int DFFc = 2048;
constexpr int Tc = Bc * Sc;   // 8192 tokens
constexpr int QKVW = 3 * Dc;  // 1536

typedef __attribute__((ext_vector_type(8))) short short8;
typedef __attribute__((ext_vector_type(4))) float f32x4;
typedef __attribute__((ext_vector_type(4))) float float4v;

static __device__ __forceinline__ float u16tof(unsigned int u) {
  return __uint_as_float(u << 16);
}
static __device__ __forceinline__ unsigned short ftobf(float f) {
  __hip_bfloat16 h = __float2bfloat16(f);
  return *reinterpret_cast<unsigned short*>(&h);
}
static __device__ __forceinline__ void gload_lds16(const void* g, void* l) {
  __builtin_amdgcn_global_load_lds(
      (const __attribute__((address_space(1))) void*)g,
      (__attribute__((address_space(3))) void*)l, 16, 0, 0);
}

// LDS chunk-swizzle helpers for attention (16B-chunk XOR, conflict-free b128)
static __device__ __forceinline__ int swzK(int row, int col) {  // width 64
  return row * 64 + ((((col >> 3) ^ (row & 7)) << 3) | (col & 7));
}
static __device__ __forceinline__ int swzW(int row, int col) {  // width 192
  return row * 192 + ((((col >> 3) ^ (row & 7)) << 3) | (col & 7));
}

// ---------------------------------------------------------------------------
// fp32 -> bf16 conversion (weights, once per launch)
// ---------------------------------------------------------------------------
__global__ __launch_bounds__(256) void k_f2bf(const float* __restrict__ in,
                                              unsigned short* __restrict__ out,
                                              int n) {
  int i = blockIdx.x * 256 + threadIdx.x;
  if (i < n) out[i] = ftobf(in[i]);
}

// ---------------------------------------------------------------------------
// Embed: h = x @ W_in^T + b_in + pos ; also bf16 copy
// ---------------------------------------------------------------------------
__global__ __launch_bounds__(256) void k_embed(const float* __restrict__ x,
                                               const float* __restrict__ W_in,
                                               const float* __restrict__ b_in,
                                               const float* __restrict__ pos,
                                               float* __restrict__ h,
                                               unsigned short* __restrict__ hb) {
  int idx = blockIdx.x * 256 + threadIdx.x;
  int t = idx >> 9;
  int d = idx & 511;
  int s = t & (Sc - 1);
  float v = x[t * 2 + 0] * W_in[d * 2 + 0] + x[t * 2 + 1] * W_in[d * 2 + 1] +
            b_in[d] + pos[(size_t)s * Dc + d];
  h[idx] = v;
  hb[idx] = ftobf(v);
}

// ---------------------------------------------------------------------------
// MFMA bf16 GEMM (round-4 proven structure): 128x128 tile, BK=32, 2-buffer,
// 4 waves (2x2), chunk-XOR-swizzled LDS (PMC-verified 0 conflicts),
// XCD block swizzle. Residual handling moved OUT (LN does it).
//   MODE 0: +bias ; MODE 2: +bias, exact GELU
//   OUTBF: 1 -> bf16 out, 0 -> fp32 out
// ---------------------------------------------------------------------------
template <int MODE, int OUTBF>
__global__ __launch_bounds__(256, 3) void k_mgemm(const unsigned short* __restrict__ A,
                                                  const unsigned short* __restrict__ W,
                                                  const float* __restrict__ bias,
                                                  void* __restrict__ Cout,
                                                  int M, int N, int K) {
  __shared__ short As[2][512 * 8];
  __shared__ short Bs[2][512 * 8];
  const int tid = threadIdx.x;
  const int lane = tid & 63;
  const int wid = tid >> 6;
  const int wm = wid >> 1;
  const int wn = wid & 1;

  // XCD-aware block swizzle (all grids used here have nwg % 8 == 0)
  const int nwg = gridDim.x * gridDim.y;
  const int bid = blockIdx.y * gridDim.x + blockIdx.x;
  const int swz = (bid & 7) * (nwg >> 3) + (bid >> 3);
  const int m0 = (swz / gridDim.x) * 128;
  const int n0 = (swz % gridDim.x) * 128;

  // staging: invert chunk-permutation p -> (row, ch) for this thread's 2 slots
  int r0S, c0S, r1S, c1S;
  {
    int p = tid;
    int rp = p >> 3, q = (p & 7) ^ (rp & 7);
    r0S = (rp << 1) | (q >> 2);
    c0S = q & 3;
    p = tid + 256;
    rp = p >> 3;
    q = (p & 7) ^ (rp & 7);
    r1S = (rp << 1) | (q >> 2);
    c1S = q & 3;
  }
  const unsigned short* a0p = A + (size_t)(m0 + r0S) * K + c0S * 8;
  const unsigned short* a1p = A + (size_t)(m0 + r1S) * K + c1S * 8;
  const unsigned short* b0p = W + (size_t)(n0 + r0S) * K + c0S * 8;
  const unsigned short* b1p = W + (size_t)(n0 + r1S) * K + c1S * 8;
  const int d0 = (tid & ~63) * 8;          // linear LDS dest (shorts)
  const int d1 = ((tid + 256) & ~63) * 8;

  f32x4 acc[4][4] = {};
  const int lr = lane & 15;
  const int chr = lane >> 4;  // fragment k-block == chunk index

  // prologue: stage tile 0 into buf 0
  gload_lds16(a0p, &As[0][d0]);
  gload_lds16(a1p, &As[0][d1]);
  gload_lds16(b0p, &Bs[0][d0]);
  gload_lds16(b1p, &Bs[0][d1]);
  __syncthreads();

  const int nsteps = K >> 5;
  int buf = 0;
  for (int s = 0; s < nsteps; ++s) {
    if (s + 1 < nsteps) {  // issue next-tile loads BEFORE consuming current
      const int ko = (s + 1) << 5;
      gload_lds16(a0p + ko, &As[buf ^ 1][d0]);
      gload_lds16(a1p + ko, &As[buf ^ 1][d1]);
      gload_lds16(b0p + ko, &Bs[buf ^ 1][d0]);
      gload_lds16(b1p + ko, &Bs[buf ^ 1][d1]);
    }
    short8 af[4], bfr[4];
#pragma unroll
    for (int mi = 0; mi < 4; ++mi) {
      int row = wm * 64 + mi * 16 + lr;
      int rp = row >> 1;
      int p = rp * 8 + (((((row & 1) << 2) | chr)) ^ (rp & 7));
      af[mi] = *(const short8*)&As[buf][p * 8];
    }
#pragma unroll
    for (int ni = 0; ni < 4; ++ni) {
      int row = wn * 64 + ni * 16 + lr;
      int rp = row >> 1;
      int p = rp * 8 + (((((row & 1) << 2) | chr)) ^ (rp & 7));
      bfr[ni] = *(const short8*)&Bs[buf][p * 8];
    }
#pragma unroll
    for (int mi = 0; mi < 4; ++mi)
#pragma unroll
      for (int ni = 0; ni < 4; ++ni)
        acc[mi][ni] = __builtin_amdgcn_mfma_f32_16x16x32_bf16(
            af[mi], bfr[ni], acc[mi][ni], 0, 0, 0);
    __syncthreads();  // drains vmcnt -> next buf ready
    buf ^= 1;
  }

  // epilogue: C/D layout col = lane&15, row = (lane>>4)*4 + j
  const int cj = lane & 15;
  const int rj = (lane >> 4) * 4;
#pragma unroll
  for (int mi = 0; mi < 4; ++mi) {
#pragma unroll
    for (int ni = 0; ni < 4; ++ni) {
      int n = n0 + wn * 64 + ni * 16 + cj;
      float bn = bias[n];
#pragma unroll
      for (int j = 0; j < 4; ++j) {
        int m = m0 + wm * 64 + mi * 16 + rj + j;
        float v = acc[mi][ni][j] + bn;
        if (MODE == 2) v = 0.5f * v * (1.0f + erff(v * 0.70710678118654752f));
        if (OUTBF)
          ((unsigned short*)Cout)[(size_t)m * N + n] = ftobf(v);
        else
          ((float*)Cout)[(size_t)m * N + n] = v;
      }
    }
  }
}

// ---------------------------------------------------------------------------
// Windowed causal attention, MFMA. qkv bf16 [T][1536].
// Block: 64 queries of one (b,h); 4 waves x 16 queries.
// ---------------------------------------------------------------------------
__global__ __launch_bounds__(256) void k_attn(const unsigned short* __restrict__ qkv,
                                              unsigned short* __restrict__ o) {
  __shared__ unsigned short Ks[192 * 64];
  __shared__ unsigned short Vt[64 * 192];
  __shared__ unsigned short Ps[64 * 192];

  const int tid = threadIdx.x;
  const int lane = tid & 63;
  const int w = tid >> 6;
  const int idx = blockIdx.x;
  const int qb = idx & 31;
  const int hh = (idx >> 5) & 7;
  const int b = idx >> 8;
  const int q0 = qb * 64;
  const int kstart = max(0, q0 - 128);
  const int nk = q0 + 64 - kstart;  // 64 (qb==0) or 192

  for (int c = tid; c < nk * 8; c += 256) {
    int j = c >> 3, ch = c & 7;
    short8 kv = *(const short8*)&qkv[(size_t)(b * Sc + kstart + j) * QKVW + Dc + hh * DHc + ch * 8];
    *(short8*)&Ks[swzK(j, ch * 8)] = kv;
  }
  for (int c = tid; c < (nk >> 1) * 8; c += 256) {
    int jp = c >> 3, ch = c & 7;
    int j = jp * 2;
    const unsigned short* base =
        &qkv[(size_t)(b * Sc + kstart + j) * QKVW + 2 * Dc + hh * DHc + ch * 8];
    short8 v0 = *(const short8*)base;
    short8 v1 = *(const short8*)(base + QKVW);
#pragma unroll
    for (int i = 0; i < 8; ++i) {
      unsigned int pk = (unsigned short)v0[i] | ((unsigned int)(unsigned short)v1[i] << 16);
      *(unsigned int*)&Vt[swzW(ch * 8 + i, j)] = pk;
    }
  }
  if (nk < 192) {
    for (int c = tid; c < 64 * 64; c += 256) {
      int d = c >> 6, jo = c & 63;
      *(unsigned int*)&Vt[swzW(d, 64 + jo * 2)] = 0;
    }
  }

  const int qg = q0 + w * 16 + (lane & 15);
  const int kg8 = (lane >> 4) * 8;
  const unsigned short* qp = &qkv[(size_t)(b * Sc + qg) * QKVW + hh * DHc + kg8];
  short8 bq0 = *(const short8*)qp;
  short8 bq1 = *(const short8*)(qp + 32);
  __syncthreads();

  const int jb = max(0, q0 + w * 16 - 128) - kstart;

  f32x4 sacc[9];
#pragma unroll
  for (int t = 0; t < 9; ++t) {
    int key = jb + t * 16 + (lane & 15);
    short8 a0 = *(const short8*)&Ks[swzK(key, kg8)];
    short8 a1 = *(const short8*)&Ks[swzK(key, 32 + kg8)];
    f32x4 z = {0.f, 0.f, 0.f, 0.f};
    z = __builtin_amdgcn_mfma_f32_16x16x32_bf16(a0, bq0, z, 0, 0, 0);
    sacc[t] = __builtin_amdgcn_mfma_f32_16x16x32_bf16(a1, bq1, z, 0, 0, 0);
  }

  const int rj = (lane >> 4) * 4;
  float mx = -1e30f;
#pragma unroll
  for (int t = 0; t < 9; ++t) {
#pragma unroll
    for (int j = 0; j < 4; ++j) {
      int kglob = kstart + jb + t * 16 + rj + j;
      bool valid = (kglob <= qg) && (kglob + 128 >= qg);
      float s = valid ? sacc[t][j] * 0.125f : -1e30f;
      sacc[t][j] = s;
      mx = fmaxf(mx, s);
    }
  }
  mx = fmaxf(mx, __shfl_xor(mx, 16));
  mx = fmaxf(mx, __shfl_xor(mx, 32));
  float sum = 0.f;
#pragma unroll
  for (int t = 0; t < 9; ++t)
#pragma unroll
    for (int j = 0; j < 4; ++j) {
      float e = __expf(sacc[t][j] - mx);
      sacc[t][j] = e;
      sum += e;
    }
  sum += __shfl_xor(sum, 16);
  sum += __shfl_xor(sum, 32);
  const float inv = 1.0f / sum;

  const int prow = w * 16 + (lane & 15);
#pragma unroll
  for (int t = 0; t < 9; ++t) {
    int c0 = jb + t * 16 + rj;
    unsigned int p0 = ftobf(sacc[t][0] * inv) |
                      ((unsigned int)ftobf(sacc[t][1] * inv) << 16);
    unsigned int p1 = ftobf(sacc[t][2] * inv) |
                      ((unsigned int)ftobf(sacc[t][3] * inv) << 16);
    *(unsigned int*)&Ps[swzW(prow, c0)] = p0;
    *(unsigned int*)&Ps[swzW(prow, c0 + 2)] = p1;
  }
  {
    int g2 = (lane >> 4) * 2;
    for (int col = g2; col < jb; col += 8)
      *(unsigned int*)&Ps[swzW(prow, col)] = 0;
    for (int col = jb + 144 + g2; col < 192; col += 8)
      *(unsigned int*)&Ps[swzW(prow, col)] = 0;
  }
  f32x4 oacc[4] = {};
#pragma unroll
  for (int kb = 0; kb < 6; ++kb) {
    short8 pa = *(const short8*)&Ps[swzW(prow, kb * 32 + kg8)];
#pragma unroll
    for (int dt = 0; dt < 4; ++dt) {
      short8 vb = *(const short8*)&Vt[swzW(dt * 16 + (lane & 15), kb * 32 + kg8)];
      oacc[dt] = __builtin_amdgcn_mfma_f32_16x16x32_bf16(pa, vb, oacc[dt], 0, 0, 0);
    }
  }
  const int cj = lane & 15;
#pragma unroll
  for (int j = 0; j < 4; ++j)
#pragma unroll
    for (int dt = 0; dt < 4; ++dt)
      o[(size_t)(b * Sc + q0 + w * 16 + rj + j) * Dc + hh * DHc + dt * 16 + cj] =
          ftobf(oacc[dt][j]);
}

// ---------------------------------------------------------------------------
// Residual + LayerNorm: h = LN(h + raw) over D=512; writes h fp32 + hb bf16.
// Identical arithmetic to the old GEMM-res + LN path: (acc+bias) + h.
// float4-vectorized loads/stores; one wave per token.
// ---------------------------------------------------------------------------
__global__ __launch_bounds__(256) void k_lnr(float* __restrict__ h,
                                             const float* __restrict__ raw,
                                             const float* __restrict__ g,
                                             const float* __restrict__ bta,
                                             unsigned short* __restrict__ outb) {
  const int wid = threadIdx.x >> 6;
  const int lane = threadIdx.x & 63;
  const int t = blockIdx.x * 4 + wid;
  const float4v* hrow = (const float4v*)(h + (size_t)t * Dc);
  const float4v* rrow = (const float4v*)(raw + (size_t)t * Dc);
  float4v v[2];
  float sum = 0.0f, sq = 0.0f;
#pragma unroll
  for (int i = 0; i < 2; ++i) {
    float4v hv = hrow[lane + i * 64];
    float4v rv = rrow[lane + i * 64];
#pragma unroll
    for (int c = 0; c < 4; ++c) {
      float xv = rv[c] + hv[c];  // (acc+bias) + h, same order as before
      v[i][c] = xv;
      sum += xv;
      sq += xv * xv;
    }
  }
#pragma unroll
  for (int off = 32; off; off >>= 1) {
    sum += __shfl_xor(sum, off);
    sq += __shfl_xor(sq, off);
  }
  float m = sum * (1.0f / 512.0f);
  float var = sq * (1.0f / 512.0f) - m * m;
  float rstd = rsqrtf(var + 1e-5f);
  float4v* orow = (float4v*)(h + (size_t)t * Dc);
  unsigned int* brow = (unsigned int*)(outb + (size_t)t * Dc);
#pragma unroll
  for (int i = 0; i < 2; ++i) {
    int d4 = (lane + i * 64) * 4;
    float4v ov;
#pragma unroll
    for (int c = 0; c < 4; ++c)
      ov[c] = (v[i][c] - m) * rstd * g[d4 + c] + bta[d4 + c];
    orow[lane + i * 64] = ov;
    unsigned int p0 = ftobf(ov[0]) | ((unsigned int)ftobf(ov[1]) << 16);
    unsigned int p1 = ftobf(ov[2]) | ((unsigned int)ftobf(ov[3]) << 16);
    brow[(lane + i * 64) * 2] = p0;
    brow[(lane + i * 64) * 2 + 1] = p1;
  }
}

// ---------------------------------------------------------------------------
// Head (fp32): mu | clipped log_sigma
// ---------------------------------------------------------------------------
__global__ __launch_bounds__(256) void k_head(const float* __restrict__ h,
                                              const float* __restrict__ Wh,
                                              const float* __restrict__ bh,
                                              float* __restrict__ outp) {
  const int wid = threadIdx.x >> 6;
  const int lane = threadIdx.x & 63;
  const int t = blockIdx.x * 4 + wid;
  const float* row = h + (size_t)t * Dc;
  float a0 = 0, a1 = 0, a2 = 0, a3 = 0;
#pragma unroll
  for (int i = 0; i < 8; ++i) {
    int d = lane + i * 64;
    float xv = row[d];
    a0 += xv * Wh[0 * Dc + d];
    a1 += xv * Wh[1 * Dc + d];
    a2 += xv * Wh[2 * Dc + d];
    a3 += xv * Wh[3 * Dc + d];
  }
#pragma unroll
  for (int off = 32; off; off >>= 1) {
    a0 += __shfl_xor(a0, off);
    a1 += __shfl_xor(a1, off);
    a2 += __shfl_xor(a2, off);
    a3 += __shfl_xor(a3, off);
  }
  if (lane == 0) {
    outp[(size_t)t * 2 + 0] = a0 + bh[0];
    outp[(size_t)t * 2 + 1] = a1 + bh[1];
    outp[(size_t)Tc * 2 + (size_t)t * 2 + 0] = fminf(fmaxf(a2 + bh[2], -6.0f), 1.5f);
    outp[(size_t)Tc * 2 + (size_t)t * 2 + 1] = fminf(fmaxf(a3 + bh[3], -6.0f), 1.5f);
  }
}

// ---------------------------------------------------------------------------
extern "C" void kernel_launch(void* const* d_in, const int* in_sizes, int n_in,
                              void* d_out, int out_size, void* d_ws, size_t ws_size,
                              hipStream_t stream) {
  const float* x    = (const float*)d_in[0];
  const float* W_in = (const float*)d_in[1];
  const float* b_in = (const float*)d_in[2];
  const float* pos  = (const float*)d_in[3];
  const float* Wqkv = (const float*)d_in[4];
  const float* bqkv = (const float*)d_in[5];
  const float* Wo   = (const float*)d_in[6];
  const float* bo   = (const float*)d_in[7];
  const float* W1   = (const float*)d_in[8];
  const float* b1   = (const float*)d_in[9];
  const float* W2   = (const float*)d_in[10];
  const float* b2   = (const float*)d_in[11];
  const float* ln1g = (const float*)d_in[12];
  const float* ln1b = (const float*)d_in[13];
  const float* ln2g = (const float*)d_in[14];
  const float* ln2b = (const float*)d_in[15];
  const float* Wh   = (const float*)d_in[16];
  const float* bh   = (const float*)d_in[17];
  float* out = (float*)d_out;

  char* p = (char*)d_ws;
  float* h   = (float*)p;          p += (size_t)Tc * Dc * 4;   // residual stream fp32
  float* t2  = (float*)p;          p += (size_t)Tc * Dc * 4;   // raw GEMM out fp32
  unsigned short* hb  = (unsigned short*)p; p += (size_t)Tc * Dc * 2;
  unsigned short* ob  = (unsigned short*)p; p += (size_t)Tc * Dc * 2;
  unsigned short* big = (unsigned short*)p; p += (size_t)Tc * DFFc * 2;
  unsigned short* wqb = (unsigned short*)p; p += (size_t)Lc * QKVW * Dc * 2;
  unsigned short* wob = (unsigned short*)p; p += (size_t)Lc * Dc * Dc * 2;
  unsigned short* w1b = (unsigned short*)p; p += (size_t)Lc * DFFc * Dc * 2;
  unsigned short* w2b = (unsigned short*)p; p += (size_t)Lc * Dc * DFFc * 2;

  k_f2bf<<<Lc * QKVW * Dc / 256, 256, 0, stream>>>(Wqkv, wqb, Lc * QKVW * Dc);
  k_f2bf<<<Lc * Dc * Dc / 256, 256, 0, stream>>>(Wo, wob, Lc * Dc * Dc);
  k_f2bf<<<Lc * DFFc * Dc / 256, 256, 0, stream>>>(W1, w1b, Lc * DFFc * Dc);
  k_f2bf<<<Lc * Dc * DFFc / 256, 256, 0, stream>>>(W2, w2b, Lc * Dc * DFFc);

  k_embed<<<(Tc * Dc) / 256, 256, 0, stream>>>(x, W_in, b_in, pos, h, hb);

  for (int l = 0; l < Lc; ++l) {
    const unsigned short* wq_l = wqb + (size_t)l * QKVW * Dc;
    const unsigned short* wo_l = wob + (size_t)l * Dc * Dc;
    const unsigned short* w1_l = w1b + (size_t)l * DFFc * Dc;
    const unsigned short* w2_l = w2b + (size_t)l * Dc * DFFc;

    // qkv = hb @ Wqkv^T + bqkv  (bf16 out)
    k_mgemm<0, 1><<<dim3(QKVW / 128, Tc / 128), 256, 0, stream>>>(
        hb, wq_l, bqkv + (size_t)l * QKVW, big, Tc, QKVW, Dc);

    k_attn<<<Bc * Hc * (Sc / 64), 256, 0, stream>>>(big, ob);

    // t2 = ob @ Wo^T + bo  (fp32 raw; residual added in LN)
    k_mgemm<0, 0><<<dim3(Dc / 128, Tc / 128), 256, 0, stream>>>(
        ob, wo_l, bo + (size_t)l * Dc, t2, Tc, Dc, Dc);

    // h = LN1(h + t2); hb = bf16(h)
    k_lnr<<<Tc / 4, 256, 0, stream>>>(h, t2, ln1g + (size_t)l * Dc,
                                      ln1b + (size_t)l * Dc, hb);

    // big = gelu(hb @ W1^T + b1)  (bf16 out)
    k_mgemm<2, 1><<<dim3(DFFc / 128, Tc / 128), 256, 0, stream>>>(
        hb, w1_l, b1 + (size_t)l * DFFc, big, Tc, DFFc, Dc);

    // t2 = big @ W2^T + b2  (fp32 raw)
    k_mgemm<0, 0><<<dim3(Dc / 128, Tc / 128), 256, 0, stream>>>(
        big, w2_l, b2 + (size_t)l * Dc, t2, Tc, Dc, DFFc);

    // h = LN2(h + t2); hb = bf16(h)
    k_lnr<<<Tc / 4, 256, 0, stream>>>(h, t2, ln2g + (size_t)l * Dc,
                                      ln2b + (size_t)l * Dc, hb);
  }

  k_head<<<Tc / 4, 256, 0, stream>>>(h, Wh, bh, out);
}

// Round 10
// 607.813 us; speedup vs baseline: 1.2657x; 1.0298x over previous
//
#include <hip/hip_runtime.h>
#include <hip/hip_bf16.h>
#include <math.h>

// Problem constants
constexpr int Bc = 4;
constexpr int Sc = 2048;
constexpr int Dc = 512;
constexpr int Hc = 8;
constexpr int DHc = 64;
constexpr int Lc = 4;
constexpr int DFFc = 2048;
constexpr int Tc = Bc * Sc;   // 8192 tokens
constexpr int QKVW = 3 * Dc;  // 1536

typedef __attribute__((ext_vector_type(8))) short short8;
typedef __attribute__((ext_vector_type(4))) float f32x4;
typedef __attribute__((ext_vector_type(4))) float float4v;
typedef __attribute__((ext_vector_type(4))) unsigned int uint4v;

static __device__ __forceinline__ float u16tof(unsigned int u) {
  return __uint_as_float(u << 16);
}
static __device__ __forceinline__ unsigned short ftobf(float f) {
  __hip_bfloat16 h = __float2bfloat16(f);
  return *reinterpret_cast<unsigned short*>(&h);
}
static __device__ __forceinline__ void gload_lds16(const void* g, void* l) {
  __builtin_amdgcn_global_load_lds(
      (const __attribute__((address_space(1))) void*)g,
      (__attribute__((address_space(3))) void*)l, 16, 0, 0);
}

// LDS chunk-swizzle helpers for attention (16B-chunk XOR, conflict-free b128)
static __device__ __forceinline__ int swzK(int row, int col) {  // width 64
  return row * 64 + ((((col >> 3) ^ (row & 7)) << 3) | (col & 7));
}
static __device__ __forceinline__ int swzW(int row, int col) {  // width 192
  return row * 192 + ((((col >> 3) ^ (row & 7)) << 3) | (col & 7));
}

// ---------------------------------------------------------------------------
// fp32 -> bf16 conversion (weights, once per launch)
// ---------------------------------------------------------------------------
__global__ __launch_bounds__(256) void k_f2bf(const float* __restrict__ in,
                                              unsigned short* __restrict__ out,
                                              int n) {
  int i = blockIdx.x * 256 + threadIdx.x;
  if (i < n) out[i] = ftobf(in[i]);
}

// ---------------------------------------------------------------------------
// Embed: h = x @ W_in^T + b_in + pos ; also bf16 copy
// ---------------------------------------------------------------------------
__global__ __launch_bounds__(256) void k_embed(const float* __restrict__ x,
                                               const float* __restrict__ W_in,
                                               const float* __restrict__ b_in,
                                               const float* __restrict__ pos,
                                               float* __restrict__ h,
                                               unsigned short* __restrict__ hb) {
  int idx = blockIdx.x * 256 + threadIdx.x;
  int t = idx >> 9;
  int d = idx & 511;
  int s = t & (Sc - 1);
  float v = x[t * 2 + 0] * W_in[d * 2 + 0] + x[t * 2 + 1] * W_in[d * 2 + 1] +
            b_in[d] + pos[(size_t)s * Dc + d];
  h[idx] = v;
  hb[idx] = ftobf(v);
}

// ---------------------------------------------------------------------------
// MFMA bf16 GEMM: 128x128 tile, BK=32, 2-buffer, 4 waves (2x2), chunk-XOR
// swizzled LDS (0 conflicts), XCD block swizzle, launch_bounds(256,3).
// NEW: LDS-transpose epilogue — scattered per-element stores replaced by
// wave-private LDS round-trip + coalesced dwordx4 stores (8 lanes = one
// contiguous 128-256B row segment). Bit-identical values.
//   MODE 0: +bias ; MODE 2: +bias, exact GELU
//   OUTBF: 1 -> bf16 out, 0 -> fp32 out
// ---------------------------------------------------------------------------
template <int MODE, int OUTBF>
__global__ __launch_bounds__(256, 3) void k_mgemm(const unsigned short* __restrict__ A,
                                                  const unsigned short* __restrict__ W,
                                                  const float* __restrict__ bias,
                                                  void* __restrict__ Cout,
                                                  int M, int N, int K) {
  // one 32 KB block: staging (As=SMEM[0], Bs=SMEM[1]) / epilogue scratch
  __shared__ short SMEM[2][2][512 * 8];
  const int tid = threadIdx.x;
  const int lane = tid & 63;
  const int wid = tid >> 6;
  const int wm = wid >> 1;
  const int wn = wid & 1;

  // XCD-aware block swizzle (all grids used here have nwg % 8 == 0)
  const int nwg = gridDim.x * gridDim.y;
  const int bid = blockIdx.y * gridDim.x + blockIdx.x;
  const int swz = (bid & 7) * (nwg >> 3) + (bid >> 3);
  const int m0 = (swz / gridDim.x) * 128;
  const int n0 = (swz % gridDim.x) * 128;

  // staging: invert chunk-permutation p -> (row, ch) for this thread's 2 slots
  int r0S, c0S, r1S, c1S;
  {
    int p = tid;
    int rp = p >> 3, q = (p & 7) ^ (rp & 7);
    r0S = (rp << 1) | (q >> 2);
    c0S = q & 3;
    p = tid + 256;
    rp = p >> 3;
    q = (p & 7) ^ (rp & 7);
    r1S = (rp << 1) | (q >> 2);
    c1S = q & 3;
  }
  const unsigned short* a0p = A + (size_t)(m0 + r0S) * K + c0S * 8;
  const unsigned short* a1p = A + (size_t)(m0 + r1S) * K + c1S * 8;
  const unsigned short* b0p = W + (size_t)(n0 + r0S) * K + c0S * 8;
  const unsigned short* b1p = W + (size_t)(n0 + r1S) * K + c1S * 8;
  const int d0 = (tid & ~63) * 8;          // linear LDS dest (shorts)
  const int d1 = ((tid + 256) & ~63) * 8;

  f32x4 acc[4][4] = {};
  const int lr = lane & 15;
  const int chr = lane >> 4;  // fragment k-block == chunk index

  // prologue: stage tile 0 into buf 0
  gload_lds16(a0p, &SMEM[0][0][d0]);
  gload_lds16(a1p, &SMEM[0][0][d1]);
  gload_lds16(b0p, &SMEM[1][0][d0]);
  gload_lds16(b1p, &SMEM[1][0][d1]);
  __syncthreads();

  const int nsteps = K >> 5;
  int buf = 0;
  for (int s = 0; s < nsteps; ++s) {
    if (s + 1 < nsteps) {  // issue next-tile loads BEFORE consuming current
      const int ko = (s + 1) << 5;
      gload_lds16(a0p + ko, &SMEM[0][buf ^ 1][d0]);
      gload_lds16(a1p + ko, &SMEM[0][buf ^ 1][d1]);
      gload_lds16(b0p + ko, &SMEM[1][buf ^ 1][d0]);
      gload_lds16(b1p + ko, &SMEM[1][buf ^ 1][d1]);
    }
    short8 af[4], bfr[4];
#pragma unroll
    for (int mi = 0; mi < 4; ++mi) {
      int row = wm * 64 + mi * 16 + lr;
      int rp = row >> 1;
      int p = rp * 8 + (((((row & 1) << 2) | chr)) ^ (rp & 7));
      af[mi] = *(const short8*)&SMEM[0][buf][p * 8];
    }
#pragma unroll
    for (int ni = 0; ni < 4; ++ni) {
      int row = wn * 64 + ni * 16 + lr;
      int rp = row >> 1;
      int p = rp * 8 + (((((row & 1) << 2) | chr)) ^ (rp & 7));
      bfr[ni] = *(const short8*)&SMEM[1][buf][p * 8];
    }
#pragma unroll
    for (int mi = 0; mi < 4; ++mi)
#pragma unroll
      for (int ni = 0; ni < 4; ++ni)
        acc[mi][ni] = __builtin_amdgcn_mfma_f32_16x16x32_bf16(
            af[mi], bfr[ni], acc[mi][ni], 0, 0, 0);
    __syncthreads();  // drains vmcnt -> next buf ready
    buf ^= 1;
  }

  // -------------------- LDS-transpose epilogue --------------------
  // Wave-private scratch: 16 rows x 68 f32 (pad 4 -> 16B-aligned b128 reads).
  // Per quarter (mi): write 16x64 f32 (bias/GELU applied), read back row-major,
  // store coalesced (8 lanes cover one row's 64 cols contiguously).
  float* cw = (float*)&SMEM[0][0][0] + wid * (16 * 68);
  const int cj = lane & 15;
  const int rj4 = (lane >> 4) * 4;
  const int rrd = lane >> 3;          // readback row within 8-row group
  const int crd = (lane & 7) * 8;     // readback col base
#pragma unroll
  for (int mi = 0; mi < 4; ++mi) {
    // write phase (applies bias / GELU, same order as before)
#pragma unroll
    for (int ni = 0; ni < 4; ++ni) {
      float bn = bias[n0 + wn * 64 + ni * 16 + cj];
#pragma unroll
      for (int j = 0; j < 4; ++j) {
        float v = acc[mi][ni][j] + bn;
        if (MODE == 2) v = 0.5f * v * (1.0f + erff(v * 0.70710678118654752f));
        cw[(rj4 + j) * 68 + ni * 16 + cj] = v;
      }
    }
    __builtin_amdgcn_sched_barrier(0);  // DS in-order per wave; pin compiler
    // read + coalesced store phase
#pragma unroll
    for (int t = 0; t < 2; ++t) {
      int rl = t * 8 + rrd;  // 0..15
      float4v v0 = *(const float4v*)&cw[rl * 68 + crd];
      float4v v1 = *(const float4v*)&cw[rl * 68 + crd + 4];
      size_t gbase = (size_t)(m0 + wm * 64 + mi * 16 + rl) * N +
                     (n0 + wn * 64 + crd);
      if (OUTBF) {
        unsigned int w0 = ftobf(v0[0]) | ((unsigned int)ftobf(v0[1]) << 16);
        unsigned int w1 = ftobf(v0[2]) | ((unsigned int)ftobf(v0[3]) << 16);
        unsigned int w2 = ftobf(v1[0]) | ((unsigned int)ftobf(v1[1]) << 16);
        unsigned int w3 = ftobf(v1[2]) | ((unsigned int)ftobf(v1[3]) << 16);
        uint4v pk = {w0, w1, w2, w3};
        *(uint4v*)&((unsigned short*)Cout)[gbase] = pk;
      } else {
        *(float4v*)&((float*)Cout)[gbase] = v0;
        *(float4v*)&((float*)Cout)[gbase + 4] = v1;
      }
    }
    __builtin_amdgcn_sched_barrier(0);  // reads of q done before q+1 writes
  }
}

// ---------------------------------------------------------------------------
// Windowed causal attention, MFMA. qkv bf16 [T][1536].
// Block: 64 queries of one (b,h); 4 waves x 16 queries.
// ---------------------------------------------------------------------------
__global__ __launch_bounds__(256) void k_attn(const unsigned short* __restrict__ qkv,
                                              unsigned short* __restrict__ o) {
  __shared__ unsigned short Ks[192 * 64];
  __shared__ unsigned short Vt[64 * 192];
  __shared__ unsigned short Ps[64 * 192];

  const int tid = threadIdx.x;
  const int lane = tid & 63;
  const int w = tid >> 6;
  const int idx = blockIdx.x;
  const int qb = idx & 31;
  const int hh = (idx >> 5) & 7;
  const int b = idx >> 8;
  const int q0 = qb * 64;
  const int kstart = max(0, q0 - 128);
  const int nk = q0 + 64 - kstart;  // 64 (qb==0) or 192

  for (int c = tid; c < nk * 8; c += 256) {
    int j = c >> 3, ch = c & 7;
    short8 kv = *(const short8*)&qkv[(size_t)(b * Sc + kstart + j) * QKVW + Dc + hh * DHc + ch * 8];
    *(short8*)&Ks[swzK(j, ch * 8)] = kv;
  }
  for (int c = tid; c < (nk >> 1) * 8; c += 256) {
    int jp = c >> 3, ch = c & 7;
    int j = jp * 2;
    const unsigned short* base =
        &qkv[(size_t)(b * Sc + kstart + j) * QKVW + 2 * Dc + hh * DHc + ch * 8];
    short8 v0 = *(const short8*)base;
    short8 v1 = *(const short8*)(base + QKVW);
#pragma unroll
    for (int i = 0; i < 8; ++i) {
      unsigned int pk = (unsigned short)v0[i] | ((unsigned int)(unsigned short)v1[i] << 16);
      *(unsigned int*)&Vt[swzW(ch * 8 + i, j)] = pk;
    }
  }
  if (nk < 192) {
    for (int c = tid; c < 64 * 64; c += 256) {
      int d = c >> 6, jo = c & 63;
      *(unsigned int*)&Vt[swzW(d, 64 + jo * 2)] = 0;
    }
  }

  const int qg = q0 + w * 16 + (lane & 15);
  const int kg8 = (lane >> 4) * 8;
  const unsigned short* qp = &qkv[(size_t)(b * Sc + qg) * QKVW + hh * DHc + kg8];
  short8 bq0 = *(const short8*)qp;
  short8 bq1 = *(const short8*)(qp + 32);
  __syncthreads();

  const int jb = max(0, q0 + w * 16 - 128) - kstart;

  f32x4 sacc[9];
#pragma unroll
  for (int t = 0; t < 9; ++t) {
    int key = jb + t * 16 + (lane & 15);
    short8 a0 = *(const short8*)&Ks[swzK(key, kg8)];
    short8 a1 = *(const short8*)&Ks[swzK(key, 32 + kg8)];
    f32x4 z = {0.f, 0.f, 0.f, 0.f};
    z = __builtin_amdgcn_mfma_f32_16x16x32_bf16(a0, bq0, z, 0, 0, 0);
    sacc[t] = __builtin_amdgcn_mfma_f32_16x16x32_bf16(a1, bq1, z, 0, 0, 0);
  }

  const int rj = (lane >> 4) * 4;
  float mx = -1e30f;
#pragma unroll
  for (int t = 0; t < 9; ++t) {
#pragma unroll
    for (int j = 0; j < 4; ++j) {
      int kglob = kstart + jb + t * 16 + rj + j;
      bool valid = (kglob <= qg) && (kglob + 128 >= qg);
      float s = valid ? sacc[t][j] * 0.125f : -1e30f;
      sacc[t][j] = s;
      mx = fmaxf(mx, s);
    }
  }
  mx = fmaxf(mx, __shfl_xor(mx, 16));
  mx = fmaxf(mx, __shfl_xor(mx, 32));
  float sum = 0.f;
#pragma unroll
  for (int t = 0; t < 9; ++t)
#pragma unroll
    for (int j = 0; j < 4; ++j) {
      float e = __expf(sacc[t][j] - mx);
      sacc[t][j] = e;
      sum += e;
    }
  sum += __shfl_xor(sum, 16);
  sum += __shfl_xor(sum, 32);
  const float inv = 1.0f / sum;

  const int prow = w * 16 + (lane & 15);
#pragma unroll
  for (int t = 0; t < 9; ++t) {
    int c0 = jb + t * 16 + rj;
    unsigned int p0 = ftobf(sacc[t][0] * inv) |
                      ((unsigned int)ftobf(sacc[t][1] * inv) << 16);
    unsigned int p1 = ftobf(sacc[t][2] * inv) |
                      ((unsigned int)ftobf(sacc[t][3] * inv) << 16);
    *(unsigned int*)&Ps[swzW(prow, c0)] = p0;
    *(unsigned int*)&Ps[swzW(prow, c0 + 2)] = p1;
  }
  {
    int g2 = (lane >> 4) * 2;
    for (int col = g2; col < jb; col += 8)
      *(unsigned int*)&Ps[swzW(prow, col)] = 0;
    for (int col = jb + 144 + g2; col < 192; col += 8)
      *(unsigned int*)&Ps[swzW(prow, col)] = 0;
  }
  f32x4 oacc[4] = {};
#pragma unroll
  for (int kb = 0; kb < 6; ++kb) {
    short8 pa = *(const short8*)&Ps[swzW(prow, kb * 32 + kg8)];
#pragma unroll
    for (int dt = 0; dt < 4; ++dt) {
      short8 vb = *(const short8*)&Vt[swzW(dt * 16 + (lane & 15), kb * 32 + kg8)];
      oacc[dt] = __builtin_amdgcn_mfma_f32_16x16x32_bf16(pa, vb, oacc[dt], 0, 0, 0);
    }
  }
  const int cj = lane & 15;
#pragma unroll
  for (int j = 0; j < 4; ++j)
#pragma unroll
    for (int dt = 0; dt < 4; ++dt)
      o[(size_t)(b * Sc + q0 + w * 16 + rj + j) * Dc + hh * DHc + dt * 16 + cj] =
          ftobf(oacc[dt][j]);
}

// ---------------------------------------------------------------------------
// Residual + LayerNorm: h = LN(h + raw) over D=512; writes h fp32 + hb bf16.
// ---------------------------------------------------------------------------
__global__ __launch_bounds__(256) void k_lnr(float* __restrict__ h,
                                             const float* __restrict__ raw,
                                             const float* __restrict__ g,
                                             const float* __restrict__ bta,
                                             unsigned short* __restrict__ outb) {
  const int wid = threadIdx.x >> 6;
  const int lane = threadIdx.x & 63;
  const int t = blockIdx.x * 4 + wid;
  const float4v* hrow = (const float4v*)(h + (size_t)t * Dc);
  const float4v* rrow = (const float4v*)(raw + (size_t)t * Dc);
  float4v v[2];
  float sum = 0.0f, sq = 0.0f;
#pragma unroll
  for (int i = 0; i < 2; ++i) {
    float4v hv = hrow[lane + i * 64];
    float4v rv = rrow[lane + i * 64];
#pragma unroll
    for (int c = 0; c < 4; ++c) {
      float xv = rv[c] + hv[c];
      v[i][c] = xv;
      sum += xv;
      sq += xv * xv;
    }
  }
#pragma unroll
  for (int off = 32; off; off >>= 1) {
    sum += __shfl_xor(sum, off);
    sq += __shfl_xor(sq, off);
  }
  float m = sum * (1.0f / 512.0f);
  float var = sq * (1.0f / 512.0f) - m * m;
  float rstd = rsqrtf(var + 1e-5f);
  float4v* orow = (float4v*)(h + (size_t)t * Dc);
  unsigned int* brow = (unsigned int*)(outb + (size_t)t * Dc);
#pragma unroll
  for (int i = 0; i < 2; ++i) {
    int d4 = (lane + i * 64) * 4;
    float4v ov;
#pragma unroll
    for (int c = 0; c < 4; ++c)
      ov[c] = (v[i][c] - m) * rstd * g[d4 + c] + bta[d4 + c];
    orow[lane + i * 64] = ov;
    unsigned int p0 = ftobf(ov[0]) | ((unsigned int)ftobf(ov[1]) << 16);
    unsigned int p1 = ftobf(ov[2]) | ((unsigned int)ftobf(ov[3]) << 16);
    brow[(lane + i * 64) * 2] = p0;
    brow[(lane + i * 64) * 2 + 1] = p1;
  }
}

// ---------------------------------------------------------------------------
// Head (fp32): mu | clipped log_sigma
// ---------------------------------------------------------------------------
__global__ __launch_bounds__(256) void k_head(const float* __restrict__ h,
                                              const float* __restrict__ Wh,
                                              const float* __restrict__ bh,
                                              float* __restrict__ outp) {
  const int wid = threadIdx.x >> 6;
  const int lane = threadIdx.x & 63;
  const int t = blockIdx.x * 4 + wid;
  const float* row = h + (size_t)t * Dc;
  float a0 = 0, a1 = 0, a2 = 0, a3 = 0;
#pragma unroll
  for (int i = 0; i < 8; ++i) {
    int d = lane + i * 64;
    float xv = row[d];
    a0 += xv * Wh[0 * Dc + d];
    a1 += xv * Wh[1 * Dc + d];
    a2 += xv * Wh[2 * Dc + d];
    a3 += xv * Wh[3 * Dc + d];
  }
#pragma unroll
  for (int off = 32; off; off >>= 1) {
    a0 += __shfl_xor(a0, off);
    a1 += __shfl_xor(a1, off);
    a2 += __shfl_xor(a2, off);
    a3 += __shfl_xor(a3, off);
  }
  if (lane == 0) {
    outp[(size_t)t * 2 + 0] = a0 + bh[0];
    outp[(size_t)t * 2 + 1] = a1 + bh[1];
    outp[(size_t)Tc * 2 + (size_t)t * 2 + 0] = fminf(fmaxf(a2 + bh[2], -6.0f), 1.5f);
    outp[(size_t)Tc * 2 + (size_t)t * 2 + 1] = fminf(fmaxf(a3 + bh[3], -6.0f), 1.5f);
  }
}

// ---------------------------------------------------------------------------
extern "C" void kernel_launch(void* const* d_in, const int* in_sizes, int n_in,
                              void* d_out, int out_size, void* d_ws, size_t ws_size,
                              hipStream_t stream) {
  const float* x    = (const float*)d_in[0];
  const float* W_in = (const float*)d_in[1];
  const float* b_in = (const float*)d_in[2];
  const float* pos  = (const float*)d_in[3];
  const float* Wqkv = (const float*)d_in[4];
  const float* bqkv = (const float*)d_in[5];
  const float* Wo   = (const float*)d_in[6];
  const float* bo   = (const float*)d_in[7];
  const float* W1   = (const float*)d_in[8];
  const float* b1   = (const float*)d_in[9];
  const float* W2   = (const float*)d_in[10];
  const float* b2   = (const float*)d_in[11];
  const float* ln1g = (const float*)d_in[12];
  const float* ln1b = (const float*)d_in[13];
  const float* ln2g = (const float*)d_in[14];
  const float* ln2b = (const float*)d_in[15];
  const float* Wh   = (const float*)d_in[16];
  const float* bh   = (const float*)d_in[17];
  float* out = (float*)d_out;

  char* p = (char*)d_ws;
  float* h   = (float*)p;          p += (size_t)Tc * Dc * 4;   // residual stream fp32
  float* t2  = (float*)p;          p += (size_t)Tc * Dc * 4;   // raw GEMM out fp32
  unsigned short* hb  = (unsigned short*)p; p += (size_t)Tc * Dc * 2;
  unsigned short* ob  = (unsigned short*)p; p += (size_t)Tc * Dc * 2;
  unsigned short* big = (unsigned short*)p; p += (size_t)Tc * DFFc * 2;
  unsigned short* wqb = (unsigned short*)p; p += (size_t)Lc * QKVW * Dc * 2;
  unsigned short* wob = (unsigned short*)p; p += (size_t)Lc * Dc * Dc * 2;
  unsigned short* w1b = (unsigned short*)p; p += (size_t)Lc * DFFc * Dc * 2;
  unsigned short* w2b = (unsigned short*)p; p += (size_t)Lc * Dc * DFFc * 2;

  k_f2bf<<<Lc * QKVW * Dc / 256, 256, 0, stream>>>(Wqkv, wqb, Lc * QKVW * Dc);
  k_f2bf<<<Lc * Dc * Dc / 256, 256, 0, stream>>>(Wo, wob, Lc * Dc * Dc);
  k_f2bf<<<Lc * DFFc * Dc / 256, 256, 0, stream>>>(W1, w1b, Lc * DFFc * Dc);
  k_f2bf<<<Lc * Dc * DFFc / 256, 256, 0, stream>>>(W2, w2b, Lc * Dc * DFFc);

  k_embed<<<(Tc * Dc) / 256, 256, 0, stream>>>(x, W_in, b_in, pos, h, hb);

  for (int l = 0; l < Lc; ++l) {
    const unsigned short* wq_l = wqb + (size_t)l * QKVW * Dc;
    const unsigned short* wo_l = wob + (size_t)l * Dc * Dc;
    const unsigned short* w1_l = w1b + (size_t)l * DFFc * Dc;
    const unsigned short* w2_l = w2b + (size_t)l * Dc * DFFc;

    // qkv = hb @ Wqkv^T + bqkv  (bf16 out)
    k_mgemm<0, 1><<<dim3(QKVW / 128, Tc / 128), 256, 0, stream>>>(
        hb, wq_l, bqkv + (size_t)l * QKVW, big, Tc, QKVW, Dc);

    k_attn<<<Bc * Hc * (Sc / 64), 256, 0, stream>>>(big, ob);

    // t2 = ob @ Wo^T + bo  (fp32 raw; residual added in LN)
    k_mgemm<0, 0><<<dim3(Dc / 128, Tc / 128), 256, 0, stream>>>(
        ob, wo_l, bo + (size_t)l * Dc, t2, Tc, Dc, Dc);

    // h = LN1(h + t2); hb = bf16(h)
    k_lnr<<<Tc / 4, 256, 0, stream>>>(h, t2, ln1g + (size_t)l * Dc,
                                      ln1b + (size_t)l * Dc, hb);

    // big = gelu(hb @ W1^T + b1)  (bf16 out)
    k_mgemm<2, 1><<<dim3(DFFc / 128, Tc / 128), 256, 0, stream>>>(
        hb, w1_l, b1 + (size_t)l * DFFc, big, Tc, DFFc, Dc);

    // t2 = big @ W2^T + b2  (fp32 raw)
    k_mgemm<0, 0><<<dim3(Dc / 128, Tc / 128), 256, 0, stream>>>(
        big, w2_l, b2 + (size_t)l * Dc, t2, Tc, Dc, DFFc);

    // h = LN2(h + t2); hb = bf16(h)
    k_lnr<<<Tc / 4, 256, 0, stream>>>(h, t2, ln2g + (size_t)l * Dc,
                                      ln2b + (size_t)l * Dc, hb);
  }

  k_head<<<Tc / 4, 256, 0, stream>>>(h, Wh, bh, out);
}

// Round 11
// 606.035 us; speedup vs baseline: 1.2694x; 1.0029x over previous
//
#include <hip/hip_runtime.h>
#include <hip/hip_bf16.h>
#include <math.h>

// Problem constants
constexpr int Bc = 4;
constexpr int Sc = 2048;
constexpr int Dc = 512;
constexpr int Hc = 8;
constexpr int DHc = 64;
constexpr int Lc = 4;
constexpr int DFFc = 2048;
constexpr int Tc = Bc * Sc;   // 8192 tokens
constexpr int QKVW = 3 * Dc;  // 1536

typedef __attribute__((ext_vector_type(8))) short short8;
typedef __attribute__((ext_vector_type(4))) float f32x4;
typedef __attribute__((ext_vector_type(4))) float float4v;
typedef __attribute__((ext_vector_type(4))) unsigned int uint4v;

static __device__ __forceinline__ float u16tof(unsigned int u) {
  return __uint_as_float(u << 16);
}
static __device__ __forceinline__ unsigned short ftobf(float f) {
  __hip_bfloat16 h = __float2bfloat16(f);
  return *reinterpret_cast<unsigned short*>(&h);
}
static __device__ __forceinline__ void gload_lds16(const void* g, void* l) {
  __builtin_amdgcn_global_load_lds(
      (const __attribute__((address_space(1))) void*)g,
      (__attribute__((address_space(3))) void*)l, 16, 0, 0);
}

// LDS chunk-swizzle helpers for attention (16B-chunk XOR, conflict-free b128)
static __device__ __forceinline__ int swzK(int row, int col) {  // width 64
  return row * 64 + ((((col >> 3) ^ (row & 7)) << 3) | (col & 7));
}
static __device__ __forceinline__ int swzW(int row, int col) {  // width 192
  return row * 192 + ((((col >> 3) ^ (row & 7)) << 3) | (col & 7));
}

// ---------------------------------------------------------------------------
// fp32 -> bf16 conversion (weights, once per launch)
// ---------------------------------------------------------------------------
__global__ __launch_bounds__(256) void k_f2bf(const float* __restrict__ in,
                                              unsigned short* __restrict__ out,
                                              int n) {
  int i = blockIdx.x * 256 + threadIdx.x;
  if (i < n) out[i] = ftobf(in[i]);
}

// ---------------------------------------------------------------------------
// Embed: h = x @ W_in^T + b_in + pos ; also bf16 copy
// ---------------------------------------------------------------------------
__global__ __launch_bounds__(256) void k_embed(const float* __restrict__ x,
                                               const float* __restrict__ W_in,
                                               const float* __restrict__ b_in,
                                               const float* __restrict__ pos,
                                               float* __restrict__ h,
                                               unsigned short* __restrict__ hb) {
  int idx = blockIdx.x * 256 + threadIdx.x;
  int t = idx >> 9;
  int d = idx & 511;
  int s = t & (Sc - 1);
  float v = x[t * 2 + 0] * W_in[d * 2 + 0] + x[t * 2 + 1] * W_in[d * 2 + 1] +
            b_in[d] + pos[(size_t)s * Dc + d];
  h[idx] = v;
  hb[idx] = ftobf(v);
}

// ---------------------------------------------------------------------------
// MFMA bf16 GEMM: 128x128 tile, BK=32, 2-buffer, 4 waves (2x2), chunk-XOR
// swizzled LDS (0 conflicts in K-loop), XCD block swizzle.
// launch_bounds(256,4): 4 blocks/CU (combined regs 120 <= 128; LDS 128 KB).
// LDS-transpose epilogue: coalesced dwordx4 stores.
//   MODE 0: +bias ; MODE 2: +bias, exact GELU
//   OUTBF: 1 -> bf16 out, 0 -> fp32 out
// ---------------------------------------------------------------------------
template <int MODE, int OUTBF>
__global__ __launch_bounds__(256, 4) void k_mgemm(const unsigned short* __restrict__ A,
                                                  const unsigned short* __restrict__ W,
                                                  const float* __restrict__ bias,
                                                  void* __restrict__ Cout,
                                                  int M, int N, int K) {
  // one 32 KB block: staging (As=SMEM[0], Bs=SMEM[1]) / epilogue scratch
  __shared__ short SMEM[2][2][512 * 8];
  const int tid = threadIdx.x;
  const int lane = tid & 63;
  const int wid = tid >> 6;
  const int wm = wid >> 1;
  const int wn = wid & 1;

  // XCD-aware block swizzle (all grids used here have nwg % 8 == 0)
  const int nwg = gridDim.x * gridDim.y;
  const int bid = blockIdx.y * gridDim.x + blockIdx.x;
  const int swz = (bid & 7) * (nwg >> 3) + (bid >> 3);
  const int m0 = (swz / gridDim.x) * 128;
  const int n0 = (swz % gridDim.x) * 128;

  // staging: invert chunk-permutation p -> (row, ch) for this thread's 2 slots
  int r0S, c0S, r1S, c1S;
  {
    int p = tid;
    int rp = p >> 3, q = (p & 7) ^ (rp & 7);
    r0S = (rp << 1) | (q >> 2);
    c0S = q & 3;
    p = tid + 256;
    rp = p >> 3;
    q = (p & 7) ^ (rp & 7);
    r1S = (rp << 1) | (q >> 2);
    c1S = q & 3;
  }
  const unsigned short* a0p = A + (size_t)(m0 + r0S) * K + c0S * 8;
  const unsigned short* a1p = A + (size_t)(m0 + r1S) * K + c1S * 8;
  const unsigned short* b0p = W + (size_t)(n0 + r0S) * K + c0S * 8;
  const unsigned short* b1p = W + (size_t)(n0 + r1S) * K + c1S * 8;
  const int d0 = (tid & ~63) * 8;          // linear LDS dest (shorts)
  const int d1 = ((tid + 256) & ~63) * 8;

  f32x4 acc[4][4] = {};
  const int lr = lane & 15;
  const int chr = lane >> 4;  // fragment k-block == chunk index

  // prologue: stage tile 0 into buf 0
  gload_lds16(a0p, &SMEM[0][0][d0]);
  gload_lds16(a1p, &SMEM[0][0][d1]);
  gload_lds16(b0p, &SMEM[1][0][d0]);
  gload_lds16(b1p, &SMEM[1][0][d1]);
  __syncthreads();

  const int nsteps = K >> 5;
  int buf = 0;
  for (int s = 0; s < nsteps; ++s) {
    if (s + 1 < nsteps) {  // issue next-tile loads BEFORE consuming current
      const int ko = (s + 1) << 5;
      gload_lds16(a0p + ko, &SMEM[0][buf ^ 1][d0]);
      gload_lds16(a1p + ko, &SMEM[0][buf ^ 1][d1]);
      gload_lds16(b0p + ko, &SMEM[1][buf ^ 1][d0]);
      gload_lds16(b1p + ko, &SMEM[1][buf ^ 1][d1]);
    }
    short8 af[4], bfr[4];
#pragma unroll
    for (int mi = 0; mi < 4; ++mi) {
      int row = wm * 64 + mi * 16 + lr;
      int rp = row >> 1;
      int p = rp * 8 + (((((row & 1) << 2) | chr)) ^ (rp & 7));
      af[mi] = *(const short8*)&SMEM[0][buf][p * 8];
    }
#pragma unroll
    for (int ni = 0; ni < 4; ++ni) {
      int row = wn * 64 + ni * 16 + lr;
      int rp = row >> 1;
      int p = rp * 8 + (((((row & 1) << 2) | chr)) ^ (rp & 7));
      bfr[ni] = *(const short8*)&SMEM[1][buf][p * 8];
    }
#pragma unroll
    for (int mi = 0; mi < 4; ++mi)
#pragma unroll
      for (int ni = 0; ni < 4; ++ni)
        acc[mi][ni] = __builtin_amdgcn_mfma_f32_16x16x32_bf16(
            af[mi], bfr[ni], acc[mi][ni], 0, 0, 0);
    __syncthreads();  // drains vmcnt -> next buf ready
    buf ^= 1;
  }

  // -------------------- LDS-transpose epilogue --------------------
  float* cw = (float*)&SMEM[0][0][0] + wid * (16 * 68);
  const int cj = lane & 15;
  const int rj4 = (lane >> 4) * 4;
  const int rrd = lane >> 3;          // readback row within 8-row group
  const int crd = (lane & 7) * 8;     // readback col base
#pragma unroll
  for (int mi = 0; mi < 4; ++mi) {
#pragma unroll
    for (int ni = 0; ni < 4; ++ni) {
      float bn = bias[n0 + wn * 64 + ni * 16 + cj];
#pragma unroll
      for (int j = 0; j < 4; ++j) {
        float v = acc[mi][ni][j] + bn;
        if (MODE == 2) v = 0.5f * v * (1.0f + erff(v * 0.70710678118654752f));
        cw[(rj4 + j) * 68 + ni * 16 + cj] = v;
      }
    }
    __builtin_amdgcn_sched_barrier(0);  // DS in-order per wave; pin compiler
#pragma unroll
    for (int t = 0; t < 2; ++t) {
      int rl = t * 8 + rrd;  // 0..15
      float4v v0 = *(const float4v*)&cw[rl * 68 + crd];
      float4v v1 = *(const float4v*)&cw[rl * 68 + crd + 4];
      size_t gbase = (size_t)(m0 + wm * 64 + mi * 16 + rl) * N +
                     (n0 + wn * 64 + crd);
      if (OUTBF) {
        unsigned int w0 = ftobf(v0[0]) | ((unsigned int)ftobf(v0[1]) << 16);
        unsigned int w1 = ftobf(v0[2]) | ((unsigned int)ftobf(v0[3]) << 16);
        unsigned int w2 = ftobf(v1[0]) | ((unsigned int)ftobf(v1[1]) << 16);
        unsigned int w3 = ftobf(v1[2]) | ((unsigned int)ftobf(v1[3]) << 16);
        uint4v pk = {w0, w1, w2, w3};
        *(uint4v*)&((unsigned short*)Cout)[gbase] = pk;
      } else {
        *(float4v*)&((float*)Cout)[gbase] = v0;
        *(float4v*)&((float*)Cout)[gbase + 4] = v1;
      }
    }
    __builtin_amdgcn_sched_barrier(0);  // reads of q done before q+1 writes
  }
}

// ---------------------------------------------------------------------------
// Windowed causal attention, MFMA. qkv bf16 [T][1536].
// Block: 64 queries of one (b,h); 4 waves x 16 queries.
// LDS 48 KB (Ps aliases Ks -- disjoint lifetimes, one extra barrier):
// 3 blocks/CU (was 2 at 72 KB).
// ---------------------------------------------------------------------------
__global__ __launch_bounds__(256, 3) void k_attn(const unsigned short* __restrict__ qkv,
                                                 unsigned short* __restrict__ o) {
  __shared__ unsigned short KPs[192 * 64];  // K rows, then reused as P
  __shared__ unsigned short Vt[64 * 192];

  const int tid = threadIdx.x;
  const int lane = tid & 63;
  const int w = tid >> 6;
  const int idx = blockIdx.x;
  const int qb = idx & 31;
  const int hh = (idx >> 5) & 7;
  const int b = idx >> 8;
  const int q0 = qb * 64;
  const int kstart = max(0, q0 - 128);
  const int nk = q0 + 64 - kstart;  // 64 (qb==0) or 192

  for (int c = tid; c < nk * 8; c += 256) {
    int j = c >> 3, ch = c & 7;
    short8 kv = *(const short8*)&qkv[(size_t)(b * Sc + kstart + j) * QKVW + Dc + hh * DHc + ch * 8];
    *(short8*)&KPs[swzK(j, ch * 8)] = kv;
  }
  for (int c = tid; c < (nk >> 1) * 8; c += 256) {
    int jp = c >> 3, ch = c & 7;
    int j = jp * 2;
    const unsigned short* base =
        &qkv[(size_t)(b * Sc + kstart + j) * QKVW + 2 * Dc + hh * DHc + ch * 8];
    short8 v0 = *(const short8*)base;
    short8 v1 = *(const short8*)(base + QKVW);
#pragma unroll
    for (int i = 0; i < 8; ++i) {
      unsigned int pk = (unsigned short)v0[i] | ((unsigned int)(unsigned short)v1[i] << 16);
      *(unsigned int*)&Vt[swzW(ch * 8 + i, j)] = pk;
    }
  }
  if (nk < 192) {  // qb==0: zero Vt cols [64,192) so P*garbage can't NaN
    for (int c = tid; c < 64 * 64; c += 256) {
      int d = c >> 6, jo = c & 63;
      *(unsigned int*)&Vt[swzW(d, 64 + jo * 2)] = 0;
    }
  }

  const int qg = q0 + w * 16 + (lane & 15);
  const int kg8 = (lane >> 4) * 8;
  const unsigned short* qp = &qkv[(size_t)(b * Sc + qg) * QKVW + hh * DHc + kg8];
  short8 bq0 = *(const short8*)qp;
  short8 bq1 = *(const short8*)(qp + 32);
  __syncthreads();

  const int jb = max(0, q0 + w * 16 - 128) - kstart;

  f32x4 sacc[9];
#pragma unroll
  for (int t = 0; t < 9; ++t) {
    int key = jb + t * 16 + (lane & 15);
    short8 a0 = *(const short8*)&KPs[swzK(key, kg8)];
    short8 a1 = *(const short8*)&KPs[swzK(key, 32 + kg8)];
    f32x4 z = {0.f, 0.f, 0.f, 0.f};
    z = __builtin_amdgcn_mfma_f32_16x16x32_bf16(a0, bq0, z, 0, 0, 0);
    sacc[t] = __builtin_amdgcn_mfma_f32_16x16x32_bf16(a1, bq1, z, 0, 0, 0);
  }

  const int rj = (lane >> 4) * 4;
  float mx = -1e30f;
#pragma unroll
  for (int t = 0; t < 9; ++t) {
#pragma unroll
    for (int j = 0; j < 4; ++j) {
      int kglob = kstart + jb + t * 16 + rj + j;
      bool valid = (kglob <= qg) && (kglob + 128 >= qg);
      float s = valid ? sacc[t][j] * 0.125f : -1e30f;
      sacc[t][j] = s;
      mx = fmaxf(mx, s);
    }
  }
  mx = fmaxf(mx, __shfl_xor(mx, 16));
  mx = fmaxf(mx, __shfl_xor(mx, 32));
  float sum = 0.f;
#pragma unroll
  for (int t = 0; t < 9; ++t)
#pragma unroll
    for (int j = 0; j < 4; ++j) {
      float e = __expf(sacc[t][j] - mx);
      sacc[t][j] = e;
      sum += e;
    }
  sum += __shfl_xor(sum, 16);
  sum += __shfl_xor(sum, 32);
  const float inv = 1.0f / sum;

  // all K reads are complete (consumed into sacc); hand KPs over to P storage
  __syncthreads();

  const int prow = w * 16 + (lane & 15);
#pragma unroll
  for (int t = 0; t < 9; ++t) {
    int c0 = jb + t * 16 + rj;
    unsigned int p0 = ftobf(sacc[t][0] * inv) |
                      ((unsigned int)ftobf(sacc[t][1] * inv) << 16);
    unsigned int p1 = ftobf(sacc[t][2] * inv) |
                      ((unsigned int)ftobf(sacc[t][3] * inv) << 16);
    *(unsigned int*)&KPs[swzW(prow, c0)] = p0;
    *(unsigned int*)&KPs[swzW(prow, c0 + 2)] = p1;
  }
  {
    int g2 = (lane >> 4) * 2;
    for (int col = g2; col < jb; col += 8)
      *(unsigned int*)&KPs[swzW(prow, col)] = 0;
    for (int col = jb + 144 + g2; col < 192; col += 8)
      *(unsigned int*)&KPs[swzW(prow, col)] = 0;
  }
  f32x4 oacc[4] = {};
#pragma unroll
  for (int kb = 0; kb < 6; ++kb) {
    short8 pa = *(const short8*)&KPs[swzW(prow, kb * 32 + kg8)];
#pragma unroll
    for (int dt = 0; dt < 4; ++dt) {
      short8 vb = *(const short8*)&Vt[swzW(dt * 16 + (lane & 15), kb * 32 + kg8)];
      oacc[dt] = __builtin_amdgcn_mfma_f32_16x16x32_bf16(pa, vb, oacc[dt], 0, 0, 0);
    }
  }
  const int cj = lane & 15;
#pragma unroll
  for (int j = 0; j < 4; ++j)
#pragma unroll
    for (int dt = 0; dt < 4; ++dt)
      o[(size_t)(b * Sc + q0 + w * 16 + rj + j) * Dc + hh * DHc + dt * 16 + cj] =
          ftobf(oacc[dt][j]);
}

// ---------------------------------------------------------------------------
// Residual + LayerNorm: h = LN(h + raw) over D=512; writes h fp32 + hb bf16.
// ---------------------------------------------------------------------------
__global__ __launch_bounds__(256) void k_lnr(float* __restrict__ h,
                                             const float* __restrict__ raw,
                                             const float* __restrict__ g,
                                             const float* __restrict__ bta,
                                             unsigned short* __restrict__ outb) {
  const int wid = threadIdx.x >> 6;
  const int lane = threadIdx.x & 63;
  const int t = blockIdx.x * 4 + wid;
  const float4v* hrow = (const float4v*)(h + (size_t)t * Dc);
  const float4v* rrow = (const float4v*)(raw + (size_t)t * Dc);
  float4v v[2];
  float sum = 0.0f, sq = 0.0f;
#pragma unroll
  for (int i = 0; i < 2; ++i) {
    float4v hv = hrow[lane + i * 64];
    float4v rv = rrow[lane + i * 64];
#pragma unroll
    for (int c = 0; c < 4; ++c) {
      float xv = rv[c] + hv[c];
      v[i][c] = xv;
      sum += xv;
      sq += xv * xv;
    }
  }
#pragma unroll
  for (int off = 32; off; off >>= 1) {
    sum += __shfl_xor(sum, off);
    sq += __shfl_xor(sq, off);
  }
  float m = sum * (1.0f / 512.0f);
  float var = sq * (1.0f / 512.0f) - m * m;
  float rstd = rsqrtf(var + 1e-5f);
  float4v* orow = (float4v*)(h + (size_t)t * Dc);
  unsigned int* brow = (unsigned int*)(outb + (size_t)t * Dc);
#pragma unroll
  for (int i = 0; i < 2; ++i) {
    int d4 = (lane + i * 64) * 4;
    float4v ov;
#pragma unroll
    for (int c = 0; c < 4; ++c)
      ov[c] = (v[i][c] - m) * rstd * g[d4 + c] + bta[d4 + c];
    orow[lane + i * 64] = ov;
    unsigned int p0 = ftobf(ov[0]) | ((unsigned int)ftobf(ov[1]) << 16);
    unsigned int p1 = ftobf(ov[2]) | ((unsigned int)ftobf(ov[3]) << 16);
    brow[(lane + i * 64) * 2] = p0;
    brow[(lane + i * 64) * 2 + 1] = p1;
  }
}

// ---------------------------------------------------------------------------
// Head (fp32): mu | clipped log_sigma
// ---------------------------------------------------------------------------
__global__ __launch_bounds__(256) void k_head(const float* __restrict__ h,
                                              const float* __restrict__ Wh,
                                              const float* __restrict__ bh,
                                              float* __restrict__ outp) {
  const int wid = threadIdx.x >> 6;
  const int lane = threadIdx.x & 63;
  const int t = blockIdx.x * 4 + wid;
  const float* row = h + (size_t)t * Dc;
  float a0 = 0, a1 = 0, a2 = 0, a3 = 0;
#pragma unroll
  for (int i = 0; i < 8; ++i) {
    int d = lane + i * 64;
    float xv = row[d];
    a0 += xv * Wh[0 * Dc + d];
    a1 += xv * Wh[1 * Dc + d];
    a2 += xv * Wh[2 * Dc + d];
    a3 += xv * Wh[3 * Dc + d];
  }
#pragma unroll
  for (int off = 32; off; off >>= 1) {
    a0 += __shfl_xor(a0, off);
    a1 += __shfl_xor(a1, off);
    a2 += __shfl_xor(a2, off);
    a3 += __shfl_xor(a3, off);
  }
  if (lane == 0) {
    outp[(size_t)t * 2 + 0] = a0 + bh[0];
    outp[(size_t)t * 2 + 1] = a1 + bh[1];
    outp[(size_t)Tc * 2 + (size_t)t * 2 + 0] = fminf(fmaxf(a2 + bh[2], -6.0f), 1.5f);
    outp[(size_t)Tc * 2 + (size_t)t * 2 + 1] = fminf(fmaxf(a3 + bh[3], -6.0f), 1.5f);
  }
}

// ---------------------------------------------------------------------------
extern "C" void kernel_launch(void* const* d_in, const int* in_sizes, int n_in,
                              void* d_out, int out_size, void* d_ws, size_t ws_size,
                              hipStream_t stream) {
  const float* x    = (const float*)d_in[0];
  const float* W_in = (const float*)d_in[1];
  const float* b_in = (const float*)d_in[2];
  const float* pos  = (const float*)d_in[3];
  const float* Wqkv = (const float*)d_in[4];
  const float* bqkv = (const float*)d_in[5];
  const float* Wo   = (const float*)d_in[6];
  const float* bo   = (const float*)d_in[7];
  const float* W1   = (const float*)d_in[8];
  const float* b1   = (const float*)d_in[9];
  const float* W2   = (const float*)d_in[10];
  const float* b2   = (const float*)d_in[11];
  const float* ln1g = (const float*)d_in[12];
  const float* ln1b = (const float*)d_in[13];
  const float* ln2g = (const float*)d_in[14];
  const float* ln2b = (const float*)d_in[15];
  const float* Wh   = (const float*)d_in[16];
  const float* bh   = (const float*)d_in[17];
  float* out = (float*)d_out;

  char* p = (char*)d_ws;
  float* h   = (float*)p;          p += (size_t)Tc * Dc * 4;   // residual stream fp32
  float* t2  = (float*)p;          p += (size_t)Tc * Dc * 4;   // raw GEMM out fp32
  unsigned short* hb  = (unsigned short*)p; p += (size_t)Tc * Dc * 2;
  unsigned short* ob  = (unsigned short*)p; p += (size_t)Tc * Dc * 2;
  unsigned short* big = (unsigned short*)p; p += (size_t)Tc * DFFc * 2;
  unsigned short* wqb = (unsigned short*)p; p += (size_t)Lc * QKVW * Dc * 2;
  unsigned short* wob = (unsigned short*)p; p += (size_t)Lc * Dc * Dc * 2;
  unsigned short* w1b = (unsigned short*)p; p += (size_t)Lc * DFFc * Dc * 2;
  unsigned short* w2b = (unsigned short*)p; p += (size_t)Lc * Dc * DFFc * 2;

  k_f2bf<<<Lc * QKVW * Dc / 256, 256, 0, stream>>>(Wqkv, wqb, Lc * QKVW * Dc);
  k_f2bf<<<Lc * Dc * Dc / 256, 256, 0, stream>>>(Wo, wob, Lc * Dc * Dc);
  k_f2bf<<<Lc * DFFc * Dc / 256, 256, 0, stream>>>(W1, w1b, Lc * DFFc * Dc);
  k_f2bf<<<Lc * Dc * DFFc / 256, 256, 0, stream>>>(W2, w2b, Lc * Dc * DFFc);

  k_embed<<<(Tc * Dc) / 256, 256, 0, stream>>>(x, W_in, b_in, pos, h, hb);

  for (int l = 0; l < Lc; ++l) {
    const unsigned short* wq_l = wqb + (size_t)l * QKVW * Dc;
    const unsigned short* wo_l = wob + (size_t)l * Dc * Dc;
    const unsigned short* w1_l = w1b + (size_t)l * DFFc * Dc;
    const unsigned short* w2_l = w2b + (size_t)l * Dc * DFFc;

    // qkv = hb @ Wqkv^T + bqkv  (bf16 out)
    k_mgemm<0, 1><<<dim3(QKVW / 128, Tc / 128), 256, 0, stream>>>(
        hb, wq_l, bqkv + (size_t)l * QKVW, big, Tc, QKVW, Dc);

    k_attn<<<Bc * Hc * (Sc / 64), 256, 0, stream>>>(big, ob);

    // t2 = ob @ Wo^T + bo  (fp32 raw; residual added in LN)
    k_mgemm<0, 0><<<dim3(Dc / 128, Tc / 128), 256, 0, stream>>>(
        ob, wo_l, bo + (size_t)l * Dc, t2, Tc, Dc, Dc);

    // h = LN1(h + t2); hb = bf16(h)
    k_lnr<<<Tc / 4, 256, 0, stream>>>(h, t2, ln1g + (size_t)l * Dc,
                                      ln1b + (size_t)l * Dc, hb);

    // big = gelu(hb @ W1^T + b1)  (bf16 out)
    k_mgemm<2, 1><<<dim3(DFFc / 128, Tc / 128), 256, 0, stream>>>(
        hb, w1_l, b1 + (size_t)l * DFFc, big, Tc, DFFc, Dc);

    // t2 = big @ W2^T + b2  (fp32 raw)
    k_mgemm<0, 0><<<dim3(Dc / 128, Tc / 128), 256, 0, stream>>>(
        big, w2_l, b2 + (size_t)l * Dc, t2, Tc, Dc, DFFc);

    // h = LN2(h + t2); hb = bf16(h)
    k_lnr<<<Tc / 4, 256, 0, stream>>>(h, t2, ln2g + (size_t)l * Dc,
                                      ln2b + (size_t)l * Dc, hb);
  }

  k_head<<<Tc / 4, 256, 0, stream>>>(h, Wh, bh, out);
}